// Round 11
// baseline (370.206 us; speedup 1.0000x reference)
//
#include <hip/hip_runtime.h>
#include <hip/hip_bf16.h>

#define NB 4
#define CC 512
#define CK 64
#define NN 4096

typedef unsigned short u16;
typedef __attribute__((ext_vector_type(8))) __bf16 bf16x8;
typedef __attribute__((ext_vector_type(4))) float f32x4;
typedef __attribute__((ext_vector_type(4))) unsigned int u32x4;
typedef __attribute__((ext_vector_type(8))) unsigned short u16x8;
typedef __attribute__((ext_vector_type(4))) unsigned short u16x4;

__device__ __forceinline__ float b2f(u16 u) {
  union { unsigned u; float f; } x; x.u = ((unsigned)u) << 16; return x.f;
}
// native RTNE f32->bf16 (compiler emits v_cvt_pk_bf16_f32; same rounding as
// the manual round-to-nearest-even bit trick, ~3x fewer VALU ops)
__device__ __forceinline__ u16 cvt_bf16(float f) {
  union { __bf16 h; u16 u; } c; c.h = (__bf16)f; return c.u;
}
// raw v_exp_f32 (2^x): single transcendental op, no libm range-fixup
__device__ __forceinline__ float fast_exp2(float x) {
  float r;
  asm("v_exp_f32 %0, %1" : "=v"(r) : "v"(x));
  return r;
}
// barrier with LDS-only drain: global loads stay in flight across it
__device__ __forceinline__ void lds_barrier() {
  asm volatile("s_waitcnt lgkmcnt(0)" ::: "memory");
  __builtin_amdgcn_s_barrier();
}

#define MFMA16(a, b, c) __builtin_amdgcn_mfma_f32_16x16x32_bf16((a), (b), (c), 0, 0, 0)

// ---------------------------------------------------------------------------
// proj_qk: Q AND K projections in one block (hi/lo bf16 decomposition).
// MERGED over the old `which` dimension: the X^T hi/lo tile (the dominant
// staging cost) is staged ONCE and consumed by both the wb and wc GEMMs.
// Q pre-scaled by log2(e) so attn softmax uses native exp2.
// grid (N/64, B), block 256 (4 waves, each 32x32 via 2x2 16x16 frags)
// ---------------------------------------------------------------------------
__global__ __launch_bounds__(256) void proj_qk(
    const float* __restrict__ x,
    const float* __restrict__ wb, const float* __restrict__ bb,
    const float* __restrict__ wc, const float* __restrict__ bc,
    u16* __restrict__ Qhi, u16* __restrict__ Qlo,
    u16* __restrict__ Khi, u16* __restrict__ Klo)
{
  const int tid = threadIdx.x;
  const int n0 = blockIdx.x * 64;
  const int b = blockIdx.y;

  __shared__ u16 Wbh[64][40], Wbl[64][40], Wch[64][40], Wcl[64][40];
  __shared__ u16 Xh[64][40], Xl[64][40];

  const int lane = tid & 63, wid = tid >> 6;
  const int wr = wid >> 1, wn = wid & 1;
  const int l15 = lane & 15, lk = (lane >> 4) * 8;

  f32x4 accb[2][2] = {}, accc[2][2] = {};

  for (int kk = 0; kk < CC; kk += 32) {
    const int row = tid >> 2, c0 = (tid & 3) * 8;
    { // stage Wb tile (64 rows x 32 c), split hi/lo
      const float* src = wb + (size_t)row * CC + kk + c0;
#pragma unroll
      for (int i = 0; i < 8; ++i) {
        float v = src[i];
        u16 h = cvt_bf16(v);
        Wbh[row][c0 + i] = h;
        Wbl[row][c0 + i] = cvt_bf16(v - b2f(h));
      }
    }
    { // stage Wc tile
      const float* src = wc + (size_t)row * CC + kk + c0;
#pragma unroll
      for (int i = 0; i < 8; ++i) {
        float v = src[i];
        u16 h = cvt_bf16(v);
        Wch[row][c0 + i] = h;
        Wcl[row][c0 + i] = cvt_bf16(v - b2f(h));
      }
    }
    { // stage X^T tile (64 n x 32 c), split hi/lo -- ONCE for both GEMMs
      const int cc2 = tid >> 3, j0 = (tid & 7) * 8;
      const float* src = x + ((size_t)b * CC + kk + cc2) * NN + n0 + j0;
#pragma unroll
      for (int i = 0; i < 8; ++i) {
        float v = src[i];
        u16 h = cvt_bf16(v);
        Xh[j0 + i][cc2] = h;
        Xl[j0 + i][cc2] = cvt_bf16(v - b2f(h));
      }
    }
    __syncthreads();
#pragma unroll
    for (int fi = 0; fi < 2; ++fi) {
      const int ar = wr * 32 + fi * 16 + l15;
      bf16x8 abh = *(const bf16x8*)&Wbh[ar][lk];
      bf16x8 abl = *(const bf16x8*)&Wbl[ar][lk];
      bf16x8 ach = *(const bf16x8*)&Wch[ar][lk];
      bf16x8 acl = *(const bf16x8*)&Wcl[ar][lk];
#pragma unroll
      for (int fj = 0; fj < 2; ++fj) {
        const int br = wn * 32 + fj * 16 + l15;
        bf16x8 bh = *(const bf16x8*)&Xh[br][lk];
        bf16x8 bl = *(const bf16x8*)&Xl[br][lk];
        accb[fi][fj] = MFMA16(abh, bh, accb[fi][fj]);
        accb[fi][fj] = MFMA16(abh, bl, accb[fi][fj]);
        accb[fi][fj] = MFMA16(abl, bh, accb[fi][fj]);
        accc[fi][fj] = MFMA16(ach, bh, accc[fi][fj]);
        accc[fi][fj] = MFMA16(ach, bl, accc[fi][fj]);
        accc[fi][fj] = MFMA16(acl, bh, accc[fi][fj]);
      }
    }
    __syncthreads();
  }

  const float qsc = 1.44269504088896340736f;  // log2(e) folded into Q
#pragma unroll
  for (int fi = 0; fi < 2; ++fi) {
    const int d0 = wr * 32 + fi * 16 + (lane >> 4) * 4;
#pragma unroll
    for (int fj = 0; fj < 2; ++fj) {
      const int n = n0 + wn * 32 + fj * 16 + l15;
      u16x4 vh, vl;
      // Q from accb (bias bb, scaled by log2e)
#pragma unroll
      for (int r = 0; r < 4; ++r) {
        float v = (accb[fi][fj][r] + bb[d0 + r]) * qsc;
        u16 h = cvt_bf16(v);
        vh[r] = h;
        vl[r] = cvt_bf16(v - b2f(h));
      }
      *(u16x4*)&Qhi[((size_t)b * NN + n) * CK + d0] = vh;
      *(u16x4*)&Qlo[((size_t)b * NN + n) * CK + d0] = vl;
      // K from accc (bias bc, unscaled)
#pragma unroll
      for (int r = 0; r < 4; ++r) {
        float v = accc[fi][fj][r] + bc[d0 + r];
        u16 h = cvt_bf16(v);
        vh[r] = h;
        vl[r] = cvt_bf16(v - b2f(h));
      }
      *(u16x4*)&Khi[((size_t)b * NN + n) * CK + d0] = vh;
      *(u16x4*)&Klo[((size_t)b * NN + n) * CK + d0] = vl;
    }
  }
}

// ---------------------------------------------------------------------------
// proj_v: feat_d projection, plain bf16. Vt[b][o][m] (m-contiguous).
// Native bf16 casts in staging/epilogue (was manual 5-op f2b).
// grid (N/64, C/64, B), block 256
// ---------------------------------------------------------------------------
__global__ __launch_bounds__(256) void proj_v(
    const float* __restrict__ x,
    const float* __restrict__ wd, const float* __restrict__ bd,
    u16* __restrict__ Vt)
{
  const int tid = threadIdx.x;
  const int n0 = blockIdx.x * 64;
  const int o0 = blockIdx.y * 64;
  const int b = blockIdx.z;

  __shared__ u16 Wt[64][40], Xt[64][40];
  const int lane = tid & 63, wid = tid >> 6;
  const int wr = wid >> 1, wn = wid & 1;
  const int l15 = lane & 15, lk = (lane >> 4) * 8;

  f32x4 acc[2][2] = {};
  for (int kk = 0; kk < CC; kk += 32) {
    {
      const int row = tid >> 2, c0 = (tid & 3) * 8;
      const float* src = wd + (size_t)(o0 + row) * CC + kk + c0;
#pragma unroll
      for (int i = 0; i < 8; ++i) Wt[row][c0 + i] = cvt_bf16(src[i]);
    }
    {
      const int cc2 = tid >> 3, j0 = (tid & 7) * 8;
      const float* src = x + ((size_t)b * CC + kk + cc2) * NN + n0 + j0;
#pragma unroll
      for (int i = 0; i < 8; ++i) Xt[j0 + i][cc2] = cvt_bf16(src[i]);
    }
    __syncthreads();
#pragma unroll
    for (int fi = 0; fi < 2; ++fi) {
      bf16x8 a = *(const bf16x8*)&Wt[wr * 32 + fi * 16 + l15][lk];
#pragma unroll
      for (int fj = 0; fj < 2; ++fj) {
        bf16x8 bv = *(const bf16x8*)&Xt[wn * 32 + fj * 16 + l15][lk];
        acc[fi][fj] = MFMA16(a, bv, acc[fi][fj]);
      }
    }
    __syncthreads();
  }
#pragma unroll
  for (int fi = 0; fi < 2; ++fi) {
    const int d0 = o0 + wr * 32 + fi * 16 + (lane >> 4) * 4;
#pragma unroll
    for (int fj = 0; fj < 2; ++fj) {
      const int n = n0 + wn * 32 + fj * 16 + l15;
#pragma unroll
      for (int r = 0; r < 4; ++r)
        Vt[((size_t)b * CC + d0 + r) * NN + n] = cvt_bf16(acc[fi][fj][r] + bd[d0 + r]);
    }
  }
}

// ---------------------------------------------------------------------------
// attn: flash attention (o-split: 2 blocks per (b,q-tile), each 256 thr =
// 4 waves, 64 q-rows x 256 o-cols; 2 blocks/CU). VERIFIED r5 version
// (231.3us total / 180.2us attn, VGPR 96, LDS 43008, 0 bank conflicts):
//   - lds_barrier (lgkmcnt-only drain): global loads stay in flight
//   - log2-domain softmax via raw v_exp_f32 (Q pre-scaled by log2e)
//   - T13 defer-max + gated O-rescale
//   - single K LDS buffer; Q frags in regs; V frags direct from global (L2)
// NOTE: structural alternatives all measured WORSE: defer-PV pipeline (r6:
// 181), 32-row q-split (r7/r8/r9: 300-394, launch_bounds hint forces 64-VGPR
// spills; 32-row geometry carries a 2^21-conflict signature), swapped-QK^T
// in-reg softmax (r10: 275, VGPR 136 -> 11% occupancy). Do not revisit
// without new counter evidence.
// grid 512, block 256
// ---------------------------------------------------------------------------
struct alignas(16) AttnLds {
  u16 kh[64][64];
  u16 kl[64][64];
  float s[64][68];   // +4 pad: fp32 score tile
  u16 p[64][64];
  float m[64];
  float l[64];
  float sc[64];
};

__global__ __launch_bounds__(256) void attn(
    const u16* __restrict__ Qhi, const u16* __restrict__ Qlo,
    const u16* __restrict__ Khi, const u16* __restrict__ Klo,
    const u16* __restrict__ Vt,
    const float* __restrict__ x, const float* __restrict__ alpha,
    float* __restrict__ out)
{
  __shared__ AttnLds L;
  const int tid = threadIdx.x;
  const int lane = tid & 63, wid = tid >> 6;   // 4 waves
  const int bid = blockIdx.x;
  // XCD-aware remap: b uses bid bits 1-2 -> batch pinned to one XCD pair
  const int b = (bid >> 1) & 3;
  const int qt = bid >> 3;        // [0,64)
  const int ohalf = bid & 1;      // o-half: columns [ohalf*256, +256)
  const int q0 = qt * 64;
  const int l15 = lane & 15;
  const int lk8 = (lane >> 4) * 8;

  // staging/softmax coords: 4 threads per row, 16 u16 (two u32x4) each
  const int srow = tid >> 2;
  const int sch  = (tid & 3) * 16;
  const int ssw0 = sch ^ ((srow & 7) << 3);
  const int ssw1 = (sch + 8) ^ ((srow & 7) << 3);

  // ---- prologue ----
  // Q fragments (iteration-invariant): wave wid owns score rows wid*16..+15
  bf16x8 qah[2], qal[2];
  {
    const size_t qg = ((size_t)b * NN + q0 + wid * 16 + l15) * CK + lk8;
    qah[0] = *(const bf16x8*)&Qhi[qg];
    qah[1] = *(const bf16x8*)&Qhi[qg + 32];
    qal[0] = *(const bf16x8*)&Qlo[qg];
    qal[1] = *(const bf16x8*)&Qlo[qg + 32];
  }
  { // K tile 0 -> LDS (swizzled)
    const size_t g = ((size_t)b * NN + srow) * CK + sch;
    *(u32x4*)&L.kh[srow][ssw0] = *(const u32x4*)&Khi[g];
    *(u32x4*)&L.kh[srow][ssw1] = *(const u32x4*)&Khi[g + 8];
    *(u32x4*)&L.kl[srow][ssw0] = *(const u32x4*)&Klo[g];
    *(u32x4*)&L.kl[srow][ssw1] = *(const u32x4*)&Klo[g + 8];
  }
  if (tid < 64) { L.m[tid] = -__builtin_huge_valf(); L.l[tid] = 0.f; }

  // per-wave V base: rows o = ohalf*256 + wid*64 + fj*16 + l15
  const u16* vbase = Vt + ((size_t)b * CC + ohalf * 256 + wid * 64 + l15) * NN + lk8;

  f32x4 accO[4][4] = {};  // [q frag][o frag]

  __syncthreads();  // K0 + m/l init visible (full barrier ok in prologue)

  for (int t = 0; t < 64; ++t) {
    const int m0 = t * 64;
    const bool hasNext = (t < 63);

    // --- issue next-K global loads (in flight across barriers) ---
    u32x4 kh0, kh1, kl0, kl1;
    if (hasNext) {
      const size_t g = ((size_t)b * NN + m0 + 64 + srow) * CK + sch;
      kh0 = *(const u32x4*)&Khi[g];
      kh1 = *(const u32x4*)&Khi[g + 8];
      kl0 = *(const u32x4*)&Klo[g];
      kl1 = *(const u32x4*)&Klo[g + 8];
    }
    // --- issue V fragment loads for THIS tile (consumed in PV) ---
    bf16x8 vr[2][4];  // [ks][fj]
#pragma unroll
    for (int f_ = 0; f_ < 4; ++f_)
#pragma unroll
      for (int ks = 0; ks < 2; ++ks)
        vr[ks][f_] = *(const bf16x8*)(vbase + (size_t)f_ * 16 * NN + m0 + ks * 32);

    // --- QK^T: wave wid does score rows wid*16, all 4 col frags ---
    __builtin_amdgcn_s_setprio(1);
#pragma unroll
    for (int fj = 0; fj < 4; ++fj) {
      f32x4 s = {};
#pragma unroll
      for (int ks = 0; ks < 2; ++ks) {
        const int k = ks * 32 + lk8;
        const int br = fj * 16 + l15;
        bf16x8 bh = *(const bf16x8*)&L.kh[br][k ^ ((br & 7) << 3)];
        bf16x8 bl = *(const bf16x8*)&L.kl[br][k ^ ((br & 7) << 3)];
        s = MFMA16(qah[ks], bh, s);
        s = MFMA16(qah[ks], bl, s);
        s = MFMA16(qal[ks], bh, s);
      }
      const int r0 = wid * 16 + (lane >> 4) * 4, c0 = fj * 16 + l15;
#pragma unroll
      for (int r = 0; r < 4; ++r) L.s[r0 + r][c0] = s[r];
    }
    __builtin_amdgcn_s_setprio(0);
    lds_barrier();  // A: s visible; QK^T K-reads + prev p-reads done

    // --- write next K tile (single buffer: reads for t done before A) ---
    if (hasNext) {
      *(u32x4*)&L.kh[srow][ssw0] = kh0;
      *(u32x4*)&L.kh[srow][ssw1] = kh1;
      *(u32x4*)&L.kl[srow][ssw0] = kl0;
      *(u32x4*)&L.kl[srow][ssw1] = kl1;
    }
    // --- online softmax (log2 domain), defer-max: 4 threads/row ---
    {
      const int row = srow, sub = tid & 3;
      const float* sr = &L.s[row][sch];
      f32x4 a0 = *(const f32x4*)&sr[0];
      f32x4 a1 = *(const f32x4*)&sr[4];
      f32x4 a2 = *(const f32x4*)&sr[8];
      f32x4 a3 = *(const f32x4*)&sr[12];
      float mx = fmaxf(fmaxf(fmaxf(a0[0], a0[1]), fmaxf(a0[2], a0[3])),
                       fmaxf(fmaxf(a1[0], a1[1]), fmaxf(a1[2], a1[3])));
      mx = fmaxf(mx, fmaxf(fmaxf(fmaxf(a2[0], a2[1]), fmaxf(a2[2], a2[3])),
                           fmaxf(fmaxf(a3[0], a3[1]), fmaxf(a3[2], a3[3]))));
      mx = fmaxf(mx, __shfl_xor(mx, 1));
      mx = fmaxf(mx, __shfl_xor(mx, 2));
      const float mOld = L.m[row];
      const bool grow = (mx > mOld + 11.5f);  // e^8 in log2 domain (T13)
      const float mNew = grow ? mx : mOld;
      float pv[16];
      float sum = 0.f;
#pragma unroll
      for (int j = 0; j < 4; ++j) { pv[j]      = fast_exp2(a0[j] - mNew); sum += pv[j]; }
#pragma unroll
      for (int j = 0; j < 4; ++j) { pv[4 + j]  = fast_exp2(a1[j] - mNew); sum += pv[4 + j]; }
#pragma unroll
      for (int j = 0; j < 4; ++j) { pv[8 + j]  = fast_exp2(a2[j] - mNew); sum += pv[8 + j]; }
#pragma unroll
      for (int j = 0; j < 4; ++j) { pv[12 + j] = fast_exp2(a3[j] - mNew); sum += pv[12 + j]; }
      sum += __shfl_xor(sum, 1);
      sum += __shfl_xor(sum, 2);
      const float scf = grow ? fast_exp2(mOld - mNew) : 1.0f;
      if (sub == 0) {
        if (grow) L.m[row] = mNew;
        L.l[row] = L.l[row] * scf + sum;
        L.sc[row] = scf;
      }
      u16x8 pb0, pb1;
#pragma unroll
      for (int j = 0; j < 8; ++j) pb0[j] = cvt_bf16(pv[j]);
#pragma unroll
      for (int j = 0; j < 8; ++j) pb1[j] = cvt_bf16(pv[8 + j]);
      *(u16x8*)&L.p[row][ssw0] = pb0;
      *(u16x8*)&L.p[row][ssw1] = pb1;
    }
    lds_barrier();  // B: p + sc + K[t+1] + m/l visible

    // --- gated rescale (usually skipped after warm-up) ---
    {
      f32x4 scv[4];
      bool need = false;
#pragma unroll
      for (int f_ = 0; f_ < 4; ++f_) {
        scv[f_] = *(const f32x4*)&L.sc[f_ * 16 + (lane >> 4) * 4];
        need |= (scv[f_][0] != 1.0f) | (scv[f_][1] != 1.0f) |
                (scv[f_][2] != 1.0f) | (scv[f_][3] != 1.0f);
      }
      if (__any(need)) {
#pragma unroll
        for (int f_ = 0; f_ < 4; ++f_)
#pragma unroll
          for (int fj = 0; fj < 4; ++fj)
#pragma unroll
            for (int r = 0; r < 4; ++r)
              accO[f_][fj][r] *= scv[f_][r];
      }
    }
    // --- PV (V operands already in regs) ---
    __builtin_amdgcn_s_setprio(1);
#pragma unroll
    for (int ks = 0; ks < 2; ++ks) {
      const int k = ks * 32 + lk8;
      bf16x8 a[4];
#pragma unroll
      for (int f_ = 0; f_ < 4; ++f_) {
        const int ar = f_ * 16 + l15;
        a[f_] = *(const bf16x8*)&L.p[ar][k ^ ((ar & 7) << 3)];
      }
#pragma unroll
      for (int fj = 0; fj < 4; ++fj)
#pragma unroll
        for (int f_ = 0; f_ < 4; ++f_)
          accO[f_][fj] = MFMA16(a[f_], vr[ks][fj], accO[f_][fj]);
    }
    __builtin_amdgcn_s_setprio(0);
  }
  __syncthreads();  // full barrier before epilogue (L.l reads)
  // epilogue: out = alpha * (O / l) + x
  const float al = alpha[0];
#pragma unroll
  for (int f_ = 0; f_ < 4; ++f_) {
    const int r0 = f_ * 16 + (lane >> 4) * 4;
    const float rl0 = 1.f / L.l[r0],     rl1 = 1.f / L.l[r0 + 1];
    const float rl2 = 1.f / L.l[r0 + 2], rl3 = 1.f / L.l[r0 + 3];
    const int n_ = q0 + r0;
#pragma unroll
    for (int fj = 0; fj < 4; ++fj) {
      const int c_ = ohalf * 256 + wid * 64 + fj * 16 + l15;
      const size_t g = ((size_t)b * CC + c_) * NN + n_;
      f32x4 xv = *(const f32x4*)&x[g];
      f32x4 ov;
      ov[0] = fmaf(al, accO[f_][fj][0] * rl0, xv[0]);
      ov[1] = fmaf(al, accO[f_][fj][1] * rl1, xv[1]);
      ov[2] = fmaf(al, accO[f_][fj][2] * rl2, xv[2]);
      ov[3] = fmaf(al, accO[f_][fj][3] * rl3, xv[3]);
      *(f32x4*)&out[g] = ov;
    }
  }
}

extern "C" void kernel_launch(void* const* d_in, const int* in_sizes, int n_in,
                              void* d_out, int out_size, void* d_ws, size_t ws_size,
                              hipStream_t stream) {
  const float* x     = (const float*)d_in[0];
  const float* wb    = (const float*)d_in[1];
  const float* bb    = (const float*)d_in[2];
  const float* wc    = (const float*)d_in[3];
  const float* bc    = (const float*)d_in[4];
  const float* wd    = (const float*)d_in[5];
  const float* bd    = (const float*)d_in[6];
  const float* alpha = (const float*)d_in[7];
  float* out = (float*)d_out;

  // workspace: Qhi|Qlo|Khi|Klo (2MB each) + Vt (16MB) = 24MB
  u16* Qhi = (u16*)d_ws;
  u16* Qlo = Qhi + (size_t)NB * NN * CK;
  u16* Khi = Qlo + (size_t)NB * NN * CK;
  u16* Klo = Khi + (size_t)NB * NN * CK;
  u16* Vt  = Klo + (size_t)NB * NN * CK;

  proj_qk<<<dim3(NN / 64, NB), 256, 0, stream>>>(x, wb, bb, wc, bc, Qhi, Qlo, Khi, Klo);
  proj_v<<<dim3(NN / 64, CC / 64, NB), 256, 0, stream>>>(x, wd, bd, Vt);
  attn<<<dim3(512), 256, 0, stream>>>(Qhi, Qlo, Khi, Klo, Vt, x, alpha, out);
}

// Round 12
// 231.719 us; speedup vs baseline: 1.5976x; 1.5976x over previous
//
#include <hip/hip_runtime.h>
#include <hip/hip_bf16.h>

#define NB 4
#define CC 512
#define CK 64
#define NN 4096

typedef unsigned short u16;
typedef __attribute__((ext_vector_type(8))) __bf16 bf16x8;
typedef __attribute__((ext_vector_type(4))) float f32x4;
typedef __attribute__((ext_vector_type(4))) unsigned int u32x4;
typedef __attribute__((ext_vector_type(8))) unsigned short u16x8;
typedef __attribute__((ext_vector_type(4))) unsigned short u16x4;

__device__ __forceinline__ u16 f2b(float f) {
  union { float f; unsigned u; } x; x.f = f;
  unsigned r = x.u + 0x7fffu + ((x.u >> 16) & 1u);
  return (u16)(r >> 16);
}
__device__ __forceinline__ float b2f(u16 u) {
  union { unsigned u; float f; } x; x.u = ((unsigned)u) << 16; return x.f;
}
__device__ __forceinline__ u16 cvt_bf16(float f) {
  union { __bf16 h; u16 u; } c; c.h = (__bf16)f; return c.u;
}
// raw v_exp_f32 (2^x): single transcendental op, no libm range-fixup
__device__ __forceinline__ float fast_exp2(float x) {
  float r;
  asm("v_exp_f32 %0, %1" : "=v"(r) : "v"(x));
  return r;
}
// barrier with LDS-only drain: global loads stay in flight across it
__device__ __forceinline__ void lds_barrier() {
  asm volatile("s_waitcnt lgkmcnt(0)" ::: "memory");
  __builtin_amdgcn_s_barrier();
}

#define MFMA16(a, b, c) __builtin_amdgcn_mfma_f32_16x16x32_bf16((a), (b), (c), 0, 0, 0)

// ---------------------------------------------------------------------------
// proj_qk: Q/K projections with hi/lo bf16 decomposition (~fp32 accuracy).
// Q additionally pre-scaled by log2(e) so attn softmax can use native exp2.
// grid (N/64, 2, B), block 256 (4 waves, each 32x32 via 2x2 16x16 frags)
// ---------------------------------------------------------------------------
__global__ __launch_bounds__(256) void proj_qk(
    const float* __restrict__ x,
    const float* __restrict__ wb, const float* __restrict__ bb,
    const float* __restrict__ wc, const float* __restrict__ bc,
    u16* __restrict__ Qhi, u16* __restrict__ Qlo,
    u16* __restrict__ Khi, u16* __restrict__ Klo)
{
  const int tid = threadIdx.x;
  const int n0 = blockIdx.x * 64;
  const int which = blockIdx.y;
  const int b = blockIdx.z;
  const float* w   = which ? wc : wb;
  const float* bia = which ? bc : bb;
  u16* oh = which ? Khi : Qhi;
  u16* ol = which ? Klo : Qlo;
  const float qsc = which ? 1.0f : 1.44269504088896340736f;  // log2(e) on Q

  __shared__ u16 Wh[64][40], Wl[64][40], Xh[64][40], Xl[64][40];

  const int lane = tid & 63, wid = tid >> 6;
  const int wr = wid >> 1, wn = wid & 1;
  const int l15 = lane & 15, lk = (lane >> 4) * 8;

  f32x4 acc[2][2] = {};

  for (int kk = 0; kk < CC; kk += 32) {
    { // stage W tile (64 rows x 32 c), split hi/lo
      const int row = tid >> 2, c0 = (tid & 3) * 8;
      const float* src = w + (size_t)row * CC + kk + c0;
#pragma unroll
      for (int i = 0; i < 8; ++i) {
        float v = src[i];
        u16 h = f2b(v);
        Wh[row][c0 + i] = h;
        Wl[row][c0 + i] = f2b(v - b2f(h));
      }
    }
    { // stage X^T tile (64 n x 32 c), split hi/lo
      const int cc2 = tid >> 3, j0 = (tid & 7) * 8;
      const float* src = x + ((size_t)b * CC + kk + cc2) * NN + n0 + j0;
#pragma unroll
      for (int i = 0; i < 8; ++i) {
        float v = src[i];
        u16 h = f2b(v);
        Xh[j0 + i][cc2] = h;
        Xl[j0 + i][cc2] = f2b(v - b2f(h));
      }
    }
    __syncthreads();
#pragma unroll
    for (int fi = 0; fi < 2; ++fi) {
      const int ar = wr * 32 + fi * 16 + l15;
      bf16x8 ah = *(const bf16x8*)&Wh[ar][lk];
      bf16x8 al = *(const bf16x8*)&Wl[ar][lk];
#pragma unroll
      for (int fj = 0; fj < 2; ++fj) {
        const int br = wn * 32 + fj * 16 + l15;
        bf16x8 bh = *(const bf16x8*)&Xh[br][lk];
        bf16x8 bl = *(const bf16x8*)&Xl[br][lk];
        acc[fi][fj] = MFMA16(ah, bh, acc[fi][fj]);
        acc[fi][fj] = MFMA16(ah, bl, acc[fi][fj]);
        acc[fi][fj] = MFMA16(al, bh, acc[fi][fj]);
      }
    }
    __syncthreads();
  }

#pragma unroll
  for (int fi = 0; fi < 2; ++fi) {
    const int d0 = wr * 32 + fi * 16 + (lane >> 4) * 4;
#pragma unroll
    for (int fj = 0; fj < 2; ++fj) {
      const int n = n0 + wn * 32 + fj * 16 + l15;
      u16x4 vh, vl;
#pragma unroll
      for (int r = 0; r < 4; ++r) {
        float v = (acc[fi][fj][r] + bia[d0 + r]) * qsc;
        u16 h = f2b(v);
        vh[r] = h;
        vl[r] = f2b(v - b2f(h));
      }
      *(u16x4*)&oh[((size_t)b * NN + n) * CK + d0] = vh;
      *(u16x4*)&ol[((size_t)b * NN + n) * CK + d0] = vl;
    }
  }
}

// ---------------------------------------------------------------------------
// proj_v: feat_d projection, plain bf16. Vt[b][o][m] (m-contiguous).
// grid (N/64, C/64, B), block 256
// ---------------------------------------------------------------------------
__global__ __launch_bounds__(256) void proj_v(
    const float* __restrict__ x,
    const float* __restrict__ wd, const float* __restrict__ bd,
    u16* __restrict__ Vt)
{
  const int tid = threadIdx.x;
  const int n0 = blockIdx.x * 64;
  const int o0 = blockIdx.y * 64;
  const int b = blockIdx.z;

  __shared__ u16 Wt[64][40], Xt[64][40];
  const int lane = tid & 63, wid = tid >> 6;
  const int wr = wid >> 1, wn = wid & 1;
  const int l15 = lane & 15, lk = (lane >> 4) * 8;

  f32x4 acc[2][2] = {};
  for (int kk = 0; kk < CC; kk += 32) {
    {
      const int row = tid >> 2, c0 = (tid & 3) * 8;
      const float* src = wd + (size_t)(o0 + row) * CC + kk + c0;
#pragma unroll
      for (int i = 0; i < 8; ++i) Wt[row][c0 + i] = f2b(src[i]);
    }
    {
      const int cc2 = tid >> 3, j0 = (tid & 7) * 8;
      const float* src = x + ((size_t)b * CC + kk + cc2) * NN + n0 + j0;
#pragma unroll
      for (int i = 0; i < 8; ++i) Xt[j0 + i][cc2] = f2b(src[i]);
    }
    __syncthreads();
#pragma unroll
    for (int fi = 0; fi < 2; ++fi) {
      bf16x8 a = *(const bf16x8*)&Wt[wr * 32 + fi * 16 + l15][lk];
#pragma unroll
      for (int fj = 0; fj < 2; ++fj) {
        bf16x8 bv = *(const bf16x8*)&Xt[wn * 32 + fj * 16 + l15][lk];
        acc[fi][fj] = MFMA16(a, bv, acc[fi][fj]);
      }
    }
    __syncthreads();
  }
#pragma unroll
  for (int fi = 0; fi < 2; ++fi) {
    const int d0 = o0 + wr * 32 + fi * 16 + (lane >> 4) * 4;
#pragma unroll
    for (int fj = 0; fj < 2; ++fj) {
      const int n = n0 + wn * 32 + fj * 16 + l15;
#pragma unroll
      for (int r = 0; r < 4; ++r)
        Vt[((size_t)b * CC + d0 + r) * NN + n] = f2b(acc[fi][fj][r] + bd[d0 + r]);
    }
  }
}

// ---------------------------------------------------------------------------
// attn: flash attention (o-split: 2 blocks per (b,q-tile), each 256 thr =
// 4 waves, 64 q-rows x 256 o-cols; 2 blocks/CU).
//   - __launch_bounds__(256, 2) is LOAD-BEARING: hint=2 -> 96 VGPR, 2
//     blocks/CU, 180us. No hint -> 132 VGPR, 1 block/CU, 315us (r11).
//     hint>=3 -> 64-VGPR spill catastrophe (r7/r8). Do not change.
//   - RAW barriers with lgkmcnt-only drain: in-loop cross-wave hazards are
//     all LDS; global loads (V frags, next-K) stay in flight.
//   - log2-domain softmax via raw v_exp_f32 (Q pre-scaled by log2e)
//   - T13 defer-max + gated O-rescale
//   - single K LDS buffer; Q frags in regs; V frags direct from global (L2)
// Structural alternatives all measured WORSE: defer-PV (r6: 181), 32-row
// q-split (r7/r8/r9: 300-394), swapped-QK^T in-reg softmax (r10: 275),
// merged proj_qk (r11: no gain). Do not revisit without new counter evidence.
// grid 512, block 256
// ---------------------------------------------------------------------------
struct alignas(16) AttnLds {
  u16 kh[64][64];
  u16 kl[64][64];
  float s[64][68];   // +4 pad: fp32 score tile
  u16 p[64][64];
  float m[64];
  float l[64];
  float sc[64];
};

__global__ __launch_bounds__(256, 2) void attn(
    const u16* __restrict__ Qhi, const u16* __restrict__ Qlo,
    const u16* __restrict__ Khi, const u16* __restrict__ Klo,
    const u16* __restrict__ Vt,
    const float* __restrict__ x, const float* __restrict__ alpha,
    float* __restrict__ out)
{
  __shared__ AttnLds L;
  const int tid = threadIdx.x;
  const int lane = tid & 63, wid = tid >> 6;   // 4 waves
  const int bid = blockIdx.x;
  // XCD-aware remap: b uses bid bits 1-2 -> batch pinned to one XCD pair
  const int b = (bid >> 1) & 3;
  const int qt = bid >> 3;        // [0,64)
  const int ohalf = bid & 1;      // o-half: columns [ohalf*256, +256)
  const int q0 = qt * 64;
  const int l15 = lane & 15;
  const int lk8 = (lane >> 4) * 8;

  // staging/softmax coords: 4 threads per row, 16 u16 (two u32x4) each
  const int srow = tid >> 2;
  const int sch  = (tid & 3) * 16;
  const int ssw0 = sch ^ ((srow & 7) << 3);
  const int ssw1 = (sch + 8) ^ ((srow & 7) << 3);

  // ---- prologue ----
  // Q fragments (iteration-invariant): wave wid owns score rows wid*16..+15
  bf16x8 qah[2], qal[2];
  {
    const size_t qg = ((size_t)b * NN + q0 + wid * 16 + l15) * CK + lk8;
    qah[0] = *(const bf16x8*)&Qhi[qg];
    qah[1] = *(const bf16x8*)&Qhi[qg + 32];
    qal[0] = *(const bf16x8*)&Qlo[qg];
    qal[1] = *(const bf16x8*)&Qlo[qg + 32];
  }
  { // K tile 0 -> LDS (swizzled)
    const size_t g = ((size_t)b * NN + srow) * CK + sch;
    *(u32x4*)&L.kh[srow][ssw0] = *(const u32x4*)&Khi[g];
    *(u32x4*)&L.kh[srow][ssw1] = *(const u32x4*)&Khi[g + 8];
    *(u32x4*)&L.kl[srow][ssw0] = *(const u32x4*)&Klo[g];
    *(u32x4*)&L.kl[srow][ssw1] = *(const u32x4*)&Klo[g + 8];
  }
  if (tid < 64) { L.m[tid] = -__builtin_huge_valf(); L.l[tid] = 0.f; }

  // per-wave V base: rows o = ohalf*256 + wid*64 + fj*16 + l15
  const u16* vbase = Vt + ((size_t)b * CC + ohalf * 256 + wid * 64 + l15) * NN + lk8;

  f32x4 accO[4][4] = {};  // [q frag][o frag]

  __syncthreads();  // K0 + m/l init visible (full barrier ok in prologue)

  for (int t = 0; t < 64; ++t) {
    const int m0 = t * 64;
    const bool hasNext = (t < 63);

    // --- issue next-K global loads (in flight across barriers) ---
    u32x4 kh0, kh1, kl0, kl1;
    if (hasNext) {
      const size_t g = ((size_t)b * NN + m0 + 64 + srow) * CK + sch;
      kh0 = *(const u32x4*)&Khi[g];
      kh1 = *(const u32x4*)&Khi[g + 8];
      kl0 = *(const u32x4*)&Klo[g];
      kl1 = *(const u32x4*)&Klo[g + 8];
    }
    // --- issue V fragment loads for THIS tile (consumed in PV) ---
    bf16x8 vr[2][4];  // [ks][fj]
#pragma unroll
    for (int f_ = 0; f_ < 4; ++f_)
#pragma unroll
      for (int ks = 0; ks < 2; ++ks)
        vr[ks][f_] = *(const bf16x8*)(vbase + (size_t)f_ * 16 * NN + m0 + ks * 32);

    // --- QK^T: wave wid does score rows wid*16, all 4 col frags ---
    __builtin_amdgcn_s_setprio(1);
#pragma unroll
    for (int fj = 0; fj < 4; ++fj) {
      f32x4 s = {};
#pragma unroll
      for (int ks = 0; ks < 2; ++ks) {
        const int k = ks * 32 + lk8;
        const int br = fj * 16 + l15;
        bf16x8 bh = *(const bf16x8*)&L.kh[br][k ^ ((br & 7) << 3)];
        bf16x8 bl = *(const bf16x8*)&L.kl[br][k ^ ((br & 7) << 3)];
        s = MFMA16(qah[ks], bh, s);
        s = MFMA16(qah[ks], bl, s);
        s = MFMA16(qal[ks], bh, s);
      }
      const int r0 = wid * 16 + (lane >> 4) * 4, c0 = fj * 16 + l15;
#pragma unroll
      for (int r = 0; r < 4; ++r) L.s[r0 + r][c0] = s[r];
    }
    __builtin_amdgcn_s_setprio(0);
    lds_barrier();  // A: s visible; QK^T K-reads + prev p-reads done

    // --- write next K tile (single buffer: reads for t done before A) ---
    if (hasNext) {
      *(u32x4*)&L.kh[srow][ssw0] = kh0;
      *(u32x4*)&L.kh[srow][ssw1] = kh1;
      *(u32x4*)&L.kl[srow][ssw0] = kl0;
      *(u32x4*)&L.kl[srow][ssw1] = kl1;
    }
    // --- online softmax (log2 domain), defer-max: 4 threads/row ---
    {
      const int row = srow, sub = tid & 3;
      const float* sr = &L.s[row][sch];
      f32x4 a0 = *(const f32x4*)&sr[0];
      f32x4 a1 = *(const f32x4*)&sr[4];
      f32x4 a2 = *(const f32x4*)&sr[8];
      f32x4 a3 = *(const f32x4*)&sr[12];
      float mx = fmaxf(fmaxf(fmaxf(a0[0], a0[1]), fmaxf(a0[2], a0[3])),
                       fmaxf(fmaxf(a1[0], a1[1]), fmaxf(a1[2], a1[3])));
      mx = fmaxf(mx, fmaxf(fmaxf(fmaxf(a2[0], a2[1]), fmaxf(a2[2], a2[3])),
                           fmaxf(fmaxf(a3[0], a3[1]), fmaxf(a3[2], a3[3]))));
      mx = fmaxf(mx, __shfl_xor(mx, 1));
      mx = fmaxf(mx, __shfl_xor(mx, 2));
      const float mOld = L.m[row];
      const bool grow = (mx > mOld + 11.5f);  // e^8 in log2 domain (T13)
      const float mNew = grow ? mx : mOld;
      float pv[16];
      float sum = 0.f;
#pragma unroll
      for (int j = 0; j < 4; ++j) { pv[j]      = fast_exp2(a0[j] - mNew); sum += pv[j]; }
#pragma unroll
      for (int j = 0; j < 4; ++j) { pv[4 + j]  = fast_exp2(a1[j] - mNew); sum += pv[4 + j]; }
#pragma unroll
      for (int j = 0; j < 4; ++j) { pv[8 + j]  = fast_exp2(a2[j] - mNew); sum += pv[8 + j]; }
#pragma unroll
      for (int j = 0; j < 4; ++j) { pv[12 + j] = fast_exp2(a3[j] - mNew); sum += pv[12 + j]; }
      sum += __shfl_xor(sum, 1);
      sum += __shfl_xor(sum, 2);
      const float scf = grow ? fast_exp2(mOld - mNew) : 1.0f;
      if (sub == 0) {
        if (grow) L.m[row] = mNew;
        L.l[row] = L.l[row] * scf + sum;
        L.sc[row] = scf;
      }
      u16x8 pb0, pb1;
#pragma unroll
      for (int j = 0; j < 8; ++j) pb0[j] = cvt_bf16(pv[j]);
#pragma unroll
      for (int j = 0; j < 8; ++j) pb1[j] = cvt_bf16(pv[8 + j]);
      *(u16x8*)&L.p[row][ssw0] = pb0;
      *(u16x8*)&L.p[row][ssw1] = pb1;
    }
    lds_barrier();  // B: p + sc + K[t+1] + m/l visible

    // --- gated rescale (usually skipped after warm-up) ---
    {
      f32x4 scv[4];
      bool need = false;
#pragma unroll
      for (int f_ = 0; f_ < 4; ++f_) {
        scv[f_] = *(const f32x4*)&L.sc[f_ * 16 + (lane >> 4) * 4];
        need |= (scv[f_][0] != 1.0f) | (scv[f_][1] != 1.0f) |
                (scv[f_][2] != 1.0f) | (scv[f_][3] != 1.0f);
      }
      if (__any(need)) {
#pragma unroll
        for (int f_ = 0; f_ < 4; ++f_)
#pragma unroll
          for (int fj = 0; fj < 4; ++fj)
#pragma unroll
            for (int r = 0; r < 4; ++r)
              accO[f_][fj][r] *= scv[f_][r];
      }
    }
    // --- PV (V operands already in regs) ---
    __builtin_amdgcn_s_setprio(1);
#pragma unroll
    for (int ks = 0; ks < 2; ++ks) {
      const int k = ks * 32 + lk8;
      bf16x8 a[4];
#pragma unroll
      for (int f_ = 0; f_ < 4; ++f_) {
        const int ar = f_ * 16 + l15;
        a[f_] = *(const bf16x8*)&L.p[ar][k ^ ((ar & 7) << 3)];
      }
#pragma unroll
      for (int fj = 0; fj < 4; ++fj)
#pragma unroll
        for (int f_ = 0; f_ < 4; ++f_)
          accO[f_][fj] = MFMA16(a[f_], vr[ks][fj], accO[f_][fj]);
    }
    __builtin_amdgcn_s_setprio(0);
  }
  __syncthreads();  // full barrier before epilogue (L.l reads)
  // epilogue: out = alpha * (O / l) + x
  const float al = alpha[0];
#pragma unroll
  for (int f_ = 0; f_ < 4; ++f_) {
    const int r0 = f_ * 16 + (lane >> 4) * 4;
    const float rl0 = 1.f / L.l[r0],     rl1 = 1.f / L.l[r0 + 1];
    const float rl2 = 1.f / L.l[r0 + 2], rl3 = 1.f / L.l[r0 + 3];
    const int n_ = q0 + r0;
#pragma unroll
    for (int fj = 0; fj < 4; ++fj) {
      const int c_ = ohalf * 256 + wid * 64 + fj * 16 + l15;
      const size_t g = ((size_t)b * CC + c_) * NN + n_;
      f32x4 xv = *(const f32x4*)&x[g];
      f32x4 ov;
      ov[0] = fmaf(al, accO[f_][fj][0] * rl0, xv[0]);
      ov[1] = fmaf(al, accO[f_][fj][1] * rl1, xv[1]);
      ov[2] = fmaf(al, accO[f_][fj][2] * rl2, xv[2]);
      ov[3] = fmaf(al, accO[f_][fj][3] * rl3, xv[3]);
      *(f32x4*)&out[g] = ov;
    }
  }
}

extern "C" void kernel_launch(void* const* d_in, const int* in_sizes, int n_in,
                              void* d_out, int out_size, void* d_ws, size_t ws_size,
                              hipStream_t stream) {
  const float* x     = (const float*)d_in[0];
  const float* wb    = (const float*)d_in[1];
  const float* bb    = (const float*)d_in[2];
  const float* wc    = (const float*)d_in[3];
  const float* bc    = (const float*)d_in[4];
  const float* wd    = (const float*)d_in[5];
  const float* bd    = (const float*)d_in[6];
  const float* alpha = (const float*)d_in[7];
  float* out = (float*)d_out;

  // workspace: Qhi|Qlo|Khi|Klo (2MB each) + Vt (16MB) = 24MB
  u16* Qhi = (u16*)d_ws;
  u16* Qlo = Qhi + (size_t)NB * NN * CK;
  u16* Khi = Qlo + (size_t)NB * NN * CK;
  u16* Klo = Khi + (size_t)NB * NN * CK;
  u16* Vt  = Klo + (size_t)NB * NN * CK;

  proj_qk<<<dim3(NN / 64, 2, NB), 256, 0, stream>>>(x, wb, bb, wc, bc, Qhi, Qlo, Khi, Klo);
  proj_v<<<dim3(NN / 64, CC / 64, NB), 256, 0, stream>>>(x, wd, bd, Vt);
  attn<<<dim3(512), 256, 0, stream>>>(Qhi, Qlo, Khi, Klo, Vt, x, alpha, out);
}

// Round 13
// 215.993 us; speedup vs baseline: 1.7140x; 1.0728x over previous
//
#include <hip/hip_runtime.h>
#include <hip/hip_bf16.h>

#define NB 4
#define CC 512
#define CK 64
#define NN 4096

typedef unsigned short u16;
typedef __attribute__((ext_vector_type(8))) __bf16 bf16x8;
typedef __attribute__((ext_vector_type(4))) float f32x4;
typedef __attribute__((ext_vector_type(4))) unsigned int u32x4;
typedef __attribute__((ext_vector_type(8))) unsigned short u16x8;
typedef __attribute__((ext_vector_type(4))) unsigned short u16x4;

__device__ __forceinline__ float b2f(u16 u) {
  union { unsigned u; float f; } x; x.u = ((unsigned)u) << 16; return x.f;
}
// native RTNE f32->bf16 cast: 1 VALU op vs the 5-op manual bit trick,
// identical round-to-nearest-even result.
__device__ __forceinline__ u16 cvt_bf16(float f) {
  union { __bf16 h; u16 u; } c; c.h = (__bf16)f; return c.u;
}
// raw v_exp_f32 (2^x): single transcendental op, no libm range-fixup
__device__ __forceinline__ float fast_exp2(float x) {
  float r;
  asm("v_exp_f32 %0, %1" : "=v"(r) : "v"(x));
  return r;
}
// barrier with LDS-only drain: global loads stay in flight across it
__device__ __forceinline__ void lds_barrier() {
  asm volatile("s_waitcnt lgkmcnt(0)" ::: "memory");
  __builtin_amdgcn_s_barrier();
}

#define MFMA16(a, b, c) __builtin_amdgcn_mfma_f32_16x16x32_bf16((a), (b), (c), 0, 0, 0)

// ---------------------------------------------------------------------------
// proj_qk: Q/K projections with hi/lo bf16 decomposition (~fp32 accuracy).
// Q additionally pre-scaled by log2(e) so attn softmax can use native exp2.
// Staging uses native cvt_bf16 (1 op, RTNE) + packed u16x8 LDS writes on the
// contiguous W path.
// grid (N/64, 2, B), block 256 (4 waves, each 32x32 via 2x2 16x16 frags)
// ---------------------------------------------------------------------------
__global__ __launch_bounds__(256) void proj_qk(
    const float* __restrict__ x,
    const float* __restrict__ wb, const float* __restrict__ bb,
    const float* __restrict__ wc, const float* __restrict__ bc,
    u16* __restrict__ Qhi, u16* __restrict__ Qlo,
    u16* __restrict__ Khi, u16* __restrict__ Klo)
{
  const int tid = threadIdx.x;
  const int n0 = blockIdx.x * 64;
  const int which = blockIdx.y;
  const int b = blockIdx.z;
  const float* w   = which ? wc : wb;
  const float* bia = which ? bc : bb;
  u16* oh = which ? Khi : Qhi;
  u16* ol = which ? Klo : Qlo;
  const float qsc = which ? 1.0f : 1.44269504088896340736f;  // log2(e) on Q

  __shared__ u16 Wh[64][40], Wl[64][40], Xh[64][40], Xl[64][40];

  const int lane = tid & 63, wid = tid >> 6;
  const int wr = wid >> 1, wn = wid & 1;
  const int l15 = lane & 15, lk = (lane >> 4) * 8;

  f32x4 acc[2][2] = {};

  for (int kk = 0; kk < CC; kk += 32) {
    { // stage W tile (64 rows x 32 c), split hi/lo; packed 16B LDS writes
      const int row = tid >> 2, c0 = (tid & 3) * 8;
      const f32x4* src = (const f32x4*)(w + (size_t)row * CC + kk + c0);
      u16x8 hh, ll;
#pragma unroll
      for (int i = 0; i < 2; ++i) {
        f32x4 v = src[i];
#pragma unroll
        for (int r = 0; r < 4; ++r) {
          u16 h = cvt_bf16(v[r]);
          hh[i * 4 + r] = h;
          ll[i * 4 + r] = cvt_bf16(v[r] - b2f(h));
        }
      }
      *(u16x8*)&Wh[row][c0] = hh;
      *(u16x8*)&Wl[row][c0] = ll;
    }
    { // stage X^T tile (64 n x 32 c), split hi/lo (transposed -> scalar LDS)
      const int cc2 = tid >> 3, j0 = (tid & 7) * 8;
      const f32x4* src = (const f32x4*)(x + ((size_t)b * CC + kk + cc2) * NN + n0 + j0);
#pragma unroll
      for (int i = 0; i < 2; ++i) {
        f32x4 v = src[i];
#pragma unroll
        for (int r = 0; r < 4; ++r) {
          u16 h = cvt_bf16(v[r]);
          Xh[j0 + i * 4 + r][cc2] = h;
          Xl[j0 + i * 4 + r][cc2] = cvt_bf16(v[r] - b2f(h));
        }
      }
    }
    __syncthreads();
#pragma unroll
    for (int fi = 0; fi < 2; ++fi) {
      const int ar = wr * 32 + fi * 16 + l15;
      bf16x8 ah = *(const bf16x8*)&Wh[ar][lk];
      bf16x8 al = *(const bf16x8*)&Wl[ar][lk];
#pragma unroll
      for (int fj = 0; fj < 2; ++fj) {
        const int br = wn * 32 + fj * 16 + l15;
        bf16x8 bh = *(const bf16x8*)&Xh[br][lk];
        bf16x8 bl = *(const bf16x8*)&Xl[br][lk];
        acc[fi][fj] = MFMA16(ah, bh, acc[fi][fj]);
        acc[fi][fj] = MFMA16(ah, bl, acc[fi][fj]);
        acc[fi][fj] = MFMA16(al, bh, acc[fi][fj]);
      }
    }
    __syncthreads();
  }

#pragma unroll
  for (int fi = 0; fi < 2; ++fi) {
    const int d0 = wr * 32 + fi * 16 + (lane >> 4) * 4;
#pragma unroll
    for (int fj = 0; fj < 2; ++fj) {
      const int n = n0 + wn * 32 + fj * 16 + l15;
      u16x4 vh, vl;
#pragma unroll
      for (int r = 0; r < 4; ++r) {
        float v = (acc[fi][fj][r] + bia[d0 + r]) * qsc;
        u16 h = cvt_bf16(v);
        vh[r] = h;
        vl[r] = cvt_bf16(v - b2f(h));
      }
      *(u16x4*)&oh[((size_t)b * NN + n) * CK + d0] = vh;
      *(u16x4*)&ol[((size_t)b * NN + n) * CK + d0] = vl;
    }
  }
}

// ---------------------------------------------------------------------------
// proj_v: feat_d projection, plain bf16. Vt[b][o][m] (m-contiguous).
// NEW: 128x128 tile (m93 geometry) - 4 waves x 4x4 16x16 frags, BK=32.
// Staging-per-FLOP halves vs the old 64x64 tile (64 MFMAs vs 8192 staged
// elems per block-iter, was 16 vs 4096). B-frags hoisted: 8 LDS reads/iter.
// grid (N/128, C/128, B) = (32, 4, 4), block 256, LDS 20KB
// ---------------------------------------------------------------------------
__global__ __launch_bounds__(256) void proj_v(
    const float* __restrict__ x,
    const float* __restrict__ wd, const float* __restrict__ bd,
    u16* __restrict__ Vt)
{
  const int tid = threadIdx.x;
  const int n0 = blockIdx.x * 128;
  const int o0 = blockIdx.y * 128;
  const int b = blockIdx.z;

  __shared__ u16 Wt[128][40], Xt[128][40];
  const int lane = tid & 63, wid = tid >> 6;
  const int wr = wid >> 1, wn = wid & 1;
  const int l15 = lane & 15, lk = (lane >> 4) * 8;

  f32x4 acc[4][4] = {};
  for (int kk = 0; kk < CC; kk += 32) {
    { // stage W tile (128 rows x 32 c): 2 threads/row, 16 floats each
      const int row = tid >> 1, c0 = (tid & 1) * 16;
      const f32x4* src = (const f32x4*)(wd + (size_t)(o0 + row) * CC + kk + c0);
#pragma unroll
      for (int i = 0; i < 4; ++i) {
        f32x4 v = src[i];
        u16x4 p;
#pragma unroll
        for (int r = 0; r < 4; ++r) p[r] = cvt_bf16(v[r]);
        *(u16x4*)&Wt[row][c0 + i * 4] = p;
      }
    }
    { // stage X^T tile (32 c x 128 n): 8 threads/c-row, 16 floats each
      const int cc2 = tid >> 3, j0 = (tid & 7) * 16;
      const f32x4* src = (const f32x4*)(x + ((size_t)b * CC + kk + cc2) * NN + n0 + j0);
#pragma unroll
      for (int i = 0; i < 4; ++i) {
        f32x4 v = src[i];
#pragma unroll
        for (int r = 0; r < 4; ++r) Xt[j0 + i * 4 + r][cc2] = cvt_bf16(v[r]);
      }
    }
    __syncthreads();
    bf16x8 bvv[4];
#pragma unroll
    for (int fj = 0; fj < 4; ++fj)
      bvv[fj] = *(const bf16x8*)&Xt[wn * 64 + fj * 16 + l15][lk];
#pragma unroll
    for (int fi = 0; fi < 4; ++fi) {
      bf16x8 a = *(const bf16x8*)&Wt[wr * 64 + fi * 16 + l15][lk];
#pragma unroll
      for (int fj = 0; fj < 4; ++fj)
        acc[fi][fj] = MFMA16(a, bvv[fj], acc[fi][fj]);
    }
    __syncthreads();
  }
#pragma unroll
  for (int fi = 0; fi < 4; ++fi) {
    const int d0 = o0 + wr * 64 + fi * 16 + (lane >> 4) * 4;
#pragma unroll
    for (int fj = 0; fj < 4; ++fj) {
      const int n = n0 + wn * 64 + fj * 16 + l15;
#pragma unroll
      for (int r = 0; r < 4; ++r)
        Vt[((size_t)b * CC + d0 + r) * NN + n] = cvt_bf16(acc[fi][fj][r] + bd[d0 + r]);
    }
  }
}

// ---------------------------------------------------------------------------
// attn: flash attention (o-split: 2 blocks per (b,q-tile), each 256 thr =
// 4 waves, 64 q-rows x 256 o-cols; 2 blocks/CU). BYTE-IDENTICAL to r12
// (verified 180.2us, VGPR 96, LDS 43008, 0 conflicts, 21% occupancy).
//   - __launch_bounds__(256, 2) is LOAD-BEARING: hint=2 -> 96 VGPR, 2
//     blocks/CU, 180us. No hint -> 132 VGPR, 1 block/CU, 315us (r11).
//     hint>=3 -> 64-VGPR spill catastrophe (r7/r8). Do not change.
//   - RAW barriers with lgkmcnt-only drain: in-loop cross-wave hazards are
//     all LDS; global loads (V frags, next-K) stay in flight.
//   - log2-domain softmax via raw v_exp_f32 (Q pre-scaled by log2e)
//   - T13 defer-max + gated O-rescale
//   - single K LDS buffer; Q frags in regs; V frags direct from global (L2)
// Structural alternatives all measured WORSE: defer-PV (r6: 181), 32-row
// q-split (r7/r8/r9: 300-394), swapped-QK^T in-reg softmax (r10: 275),
// merged proj_qk (r11: no gain). Do not revisit without new counter evidence.
// grid 512, block 256
// ---------------------------------------------------------------------------
struct alignas(16) AttnLds {
  u16 kh[64][64];
  u16 kl[64][64];
  float s[64][68];   // +4 pad: fp32 score tile
  u16 p[64][64];
  float m[64];
  float l[64];
  float sc[64];
};

__global__ __launch_bounds__(256, 2) void attn(
    const u16* __restrict__ Qhi, const u16* __restrict__ Qlo,
    const u16* __restrict__ Khi, const u16* __restrict__ Klo,
    const u16* __restrict__ Vt,
    const float* __restrict__ x, const float* __restrict__ alpha,
    float* __restrict__ out)
{
  __shared__ AttnLds L;
  const int tid = threadIdx.x;
  const int lane = tid & 63, wid = tid >> 6;   // 4 waves
  const int bid = blockIdx.x;
  // XCD-aware remap: b uses bid bits 1-2 -> batch pinned to one XCD pair
  const int b = (bid >> 1) & 3;
  const int qt = bid >> 3;        // [0,64)
  const int ohalf = bid & 1;      // o-half: columns [ohalf*256, +256)
  const int q0 = qt * 64;
  const int l15 = lane & 15;
  const int lk8 = (lane >> 4) * 8;

  // staging/softmax coords: 4 threads per row, 16 u16 (two u32x4) each
  const int srow = tid >> 2;
  const int sch  = (tid & 3) * 16;
  const int ssw0 = sch ^ ((srow & 7) << 3);
  const int ssw1 = (sch + 8) ^ ((srow & 7) << 3);

  // ---- prologue ----
  // Q fragments (iteration-invariant): wave wid owns score rows wid*16..+15
  bf16x8 qah[2], qal[2];
  {
    const size_t qg = ((size_t)b * NN + q0 + wid * 16 + l15) * CK + lk8;
    qah[0] = *(const bf16x8*)&Qhi[qg];
    qah[1] = *(const bf16x8*)&Qhi[qg + 32];
    qal[0] = *(const bf16x8*)&Qlo[qg];
    qal[1] = *(const bf16x8*)&Qlo[qg + 32];
  }
  { // K tile 0 -> LDS (swizzled)
    const size_t g = ((size_t)b * NN + srow) * CK + sch;
    *(u32x4*)&L.kh[srow][ssw0] = *(const u32x4*)&Khi[g];
    *(u32x4*)&L.kh[srow][ssw1] = *(const u32x4*)&Khi[g + 8];
    *(u32x4*)&L.kl[srow][ssw0] = *(const u32x4*)&Klo[g];
    *(u32x4*)&L.kl[srow][ssw1] = *(const u32x4*)&Klo[g + 8];
  }
  if (tid < 64) { L.m[tid] = -__builtin_huge_valf(); L.l[tid] = 0.f; }

  // per-wave V base: rows o = ohalf*256 + wid*64 + fj*16 + l15
  const u16* vbase = Vt + ((size_t)b * CC + ohalf * 256 + wid * 64 + l15) * NN + lk8;

  f32x4 accO[4][4] = {};  // [q frag][o frag]

  __syncthreads();  // K0 + m/l init visible (full barrier ok in prologue)

  for (int t = 0; t < 64; ++t) {
    const int m0 = t * 64;
    const bool hasNext = (t < 63);

    // --- issue next-K global loads (in flight across barriers) ---
    u32x4 kh0, kh1, kl0, kl1;
    if (hasNext) {
      const size_t g = ((size_t)b * NN + m0 + 64 + srow) * CK + sch;
      kh0 = *(const u32x4*)&Khi[g];
      kh1 = *(const u32x4*)&Khi[g + 8];
      kl0 = *(const u32x4*)&Klo[g];
      kl1 = *(const u32x4*)&Klo[g + 8];
    }
    // --- issue V fragment loads for THIS tile (consumed in PV) ---
    bf16x8 vr[2][4];  // [ks][fj]
#pragma unroll
    for (int f_ = 0; f_ < 4; ++f_)
#pragma unroll
      for (int ks = 0; ks < 2; ++ks)
        vr[ks][f_] = *(const bf16x8*)(vbase + (size_t)f_ * 16 * NN + m0 + ks * 32);

    // --- QK^T: wave wid does score rows wid*16, all 4 col frags ---
    __builtin_amdgcn_s_setprio(1);
#pragma unroll
    for (int fj = 0; fj < 4; ++fj) {
      f32x4 s = {};
#pragma unroll
      for (int ks = 0; ks < 2; ++ks) {
        const int k = ks * 32 + lk8;
        const int br = fj * 16 + l15;
        bf16x8 bh = *(const bf16x8*)&L.kh[br][k ^ ((br & 7) << 3)];
        bf16x8 bl = *(const bf16x8*)&L.kl[br][k ^ ((br & 7) << 3)];
        s = MFMA16(qah[ks], bh, s);
        s = MFMA16(qah[ks], bl, s);
        s = MFMA16(qal[ks], bh, s);
      }
      const int r0 = wid * 16 + (lane >> 4) * 4, c0 = fj * 16 + l15;
#pragma unroll
      for (int r = 0; r < 4; ++r) L.s[r0 + r][c0] = s[r];
    }
    __builtin_amdgcn_s_setprio(0);
    lds_barrier();  // A: s visible; QK^T K-reads + prev p-reads done

    // --- write next K tile (single buffer: reads for t done before A) ---
    if (hasNext) {
      *(u32x4*)&L.kh[srow][ssw0] = kh0;
      *(u32x4*)&L.kh[srow][ssw1] = kh1;
      *(u32x4*)&L.kl[srow][ssw0] = kl0;
      *(u32x4*)&L.kl[srow][ssw1] = kl1;
    }
    // --- online softmax (log2 domain), defer-max: 4 threads/row ---
    {
      const int row = srow, sub = tid & 3;
      const float* sr = &L.s[row][sch];
      f32x4 a0 = *(const f32x4*)&sr[0];
      f32x4 a1 = *(const f32x4*)&sr[4];
      f32x4 a2 = *(const f32x4*)&sr[8];
      f32x4 a3 = *(const f32x4*)&sr[12];
      float mx = fmaxf(fmaxf(fmaxf(a0[0], a0[1]), fmaxf(a0[2], a0[3])),
                       fmaxf(fmaxf(a1[0], a1[1]), fmaxf(a1[2], a1[3])));
      mx = fmaxf(mx, fmaxf(fmaxf(fmaxf(a2[0], a2[1]), fmaxf(a2[2], a2[3])),
                           fmaxf(fmaxf(a3[0], a3[1]), fmaxf(a3[2], a3[3]))));
      mx = fmaxf(mx, __shfl_xor(mx, 1));
      mx = fmaxf(mx, __shfl_xor(mx, 2));
      const float mOld = L.m[row];
      const bool grow = (mx > mOld + 11.5f);  // e^8 in log2 domain (T13)
      const float mNew = grow ? mx : mOld;
      float pv[16];
      float sum = 0.f;
#pragma unroll
      for (int j = 0; j < 4; ++j) { pv[j]      = fast_exp2(a0[j] - mNew); sum += pv[j]; }
#pragma unroll
      for (int j = 0; j < 4; ++j) { pv[4 + j]  = fast_exp2(a1[j] - mNew); sum += pv[4 + j]; }
#pragma unroll
      for (int j = 0; j < 4; ++j) { pv[8 + j]  = fast_exp2(a2[j] - mNew); sum += pv[8 + j]; }
#pragma unroll
      for (int j = 0; j < 4; ++j) { pv[12 + j] = fast_exp2(a3[j] - mNew); sum += pv[12 + j]; }
      sum += __shfl_xor(sum, 1);
      sum += __shfl_xor(sum, 2);
      const float scf = grow ? fast_exp2(mOld - mNew) : 1.0f;
      if (sub == 0) {
        if (grow) L.m[row] = mNew;
        L.l[row] = L.l[row] * scf + sum;
        L.sc[row] = scf;
      }
      u16x8 pb0, pb1;
#pragma unroll
      for (int j = 0; j < 8; ++j) pb0[j] = cvt_bf16(pv[j]);
#pragma unroll
      for (int j = 0; j < 8; ++j) pb1[j] = cvt_bf16(pv[8 + j]);
      *(u16x8*)&L.p[row][ssw0] = pb0;
      *(u16x8*)&L.p[row][ssw1] = pb1;
    }
    lds_barrier();  // B: p + sc + K[t+1] + m/l visible

    // --- gated rescale (usually skipped after warm-up) ---
    {
      f32x4 scv[4];
      bool need = false;
#pragma unroll
      for (int f_ = 0; f_ < 4; ++f_) {
        scv[f_] = *(const f32x4*)&L.sc[f_ * 16 + (lane >> 4) * 4];
        need |= (scv[f_][0] != 1.0f) | (scv[f_][1] != 1.0f) |
                (scv[f_][2] != 1.0f) | (scv[f_][3] != 1.0f);
      }
      if (__any(need)) {
#pragma unroll
        for (int f_ = 0; f_ < 4; ++f_)
#pragma unroll
          for (int fj = 0; fj < 4; ++fj)
#pragma unroll
            for (int r = 0; r < 4; ++r)
              accO[f_][fj][r] *= scv[f_][r];
      }
    }
    // --- PV (V operands already in regs) ---
    __builtin_amdgcn_s_setprio(1);
#pragma unroll
    for (int ks = 0; ks < 2; ++ks) {
      const int k = ks * 32 + lk8;
      bf16x8 a[4];
#pragma unroll
      for (int f_ = 0; f_ < 4; ++f_) {
        const int ar = f_ * 16 + l15;
        a[f_] = *(const bf16x8*)&L.p[ar][k ^ ((ar & 7) << 3)];
      }
#pragma unroll
      for (int fj = 0; fj < 4; ++fj)
#pragma unroll
        for (int f_ = 0; f_ < 4; ++f_)
          accO[f_][fj] = MFMA16(a[f_], vr[ks][fj], accO[f_][fj]);
    }
    __builtin_amdgcn_s_setprio(0);
  }
  __syncthreads();  // full barrier before epilogue (L.l reads)
  // epilogue: out = alpha * (O / l) + x
  const float al = alpha[0];
#pragma unroll
  for (int f_ = 0; f_ < 4; ++f_) {
    const int r0 = f_ * 16 + (lane >> 4) * 4;
    const float rl0 = 1.f / L.l[r0],     rl1 = 1.f / L.l[r0 + 1];
    const float rl2 = 1.f / L.l[r0 + 2], rl3 = 1.f / L.l[r0 + 3];
    const int n_ = q0 + r0;
#pragma unroll
    for (int fj = 0; fj < 4; ++fj) {
      const int c_ = ohalf * 256 + wid * 64 + fj * 16 + l15;
      const size_t g = ((size_t)b * CC + c_) * NN + n_;
      f32x4 xv = *(const f32x4*)&x[g];
      f32x4 ov;
      ov[0] = fmaf(al, accO[f_][fj][0] * rl0, xv[0]);
      ov[1] = fmaf(al, accO[f_][fj][1] * rl1, xv[1]);
      ov[2] = fmaf(al, accO[f_][fj][2] * rl2, xv[2]);
      ov[3] = fmaf(al, accO[f_][fj][3] * rl3, xv[3]);
      *(f32x4*)&out[g] = ov;
    }
  }
}

extern "C" void kernel_launch(void* const* d_in, const int* in_sizes, int n_in,
                              void* d_out, int out_size, void* d_ws, size_t ws_size,
                              hipStream_t stream) {
  const float* x     = (const float*)d_in[0];
  const float* wb    = (const float*)d_in[1];
  const float* bb    = (const float*)d_in[2];
  const float* wc    = (const float*)d_in[3];
  const float* bc    = (const float*)d_in[4];
  const float* wd    = (const float*)d_in[5];
  const float* bd    = (const float*)d_in[6];
  const float* alpha = (const float*)d_in[7];
  float* out = (float*)d_out;

  // workspace: Qhi|Qlo|Khi|Klo (2MB each) + Vt (16MB) = 24MB
  u16* Qhi = (u16*)d_ws;
  u16* Qlo = Qhi + (size_t)NB * NN * CK;
  u16* Khi = Qlo + (size_t)NB * NN * CK;
  u16* Klo = Khi + (size_t)NB * NN * CK;
  u16* Vt  = Klo + (size_t)NB * NN * CK;

  proj_qk<<<dim3(NN / 64, 2, NB), 256, 0, stream>>>(x, wb, bb, wc, bc, Qhi, Qlo, Khi, Klo);
  proj_v<<<dim3(NN / 128, CC / 128, NB), 256, 0, stream>>>(x, wd, bd, Vt);
  attn<<<dim3(512), 256, 0, stream>>>(Qhi, Qlo, Khi, Klo, Vt, x, alpha, out);
}

// Round 14
// 211.798 us; speedup vs baseline: 1.7479x; 1.0198x over previous
//
#include <hip/hip_runtime.h>
#include <hip/hip_bf16.h>

#define NB 4
#define CC 512
#define CK 64
#define NN 4096

typedef unsigned short u16;
typedef __attribute__((ext_vector_type(8))) __bf16 bf16x8;
typedef __attribute__((ext_vector_type(4))) float f32x4;
typedef __attribute__((ext_vector_type(4))) unsigned int u32x4;
typedef __attribute__((ext_vector_type(8))) unsigned short u16x8;
typedef __attribute__((ext_vector_type(4))) unsigned short u16x4;

__device__ __forceinline__ float b2f(u16 u) {
  union { unsigned u; float f; } x; x.u = ((unsigned)u) << 16; return x.f;
}
// native RTNE f32->bf16 cast: 1 VALU op, identical rounding to the manual trick
__device__ __forceinline__ u16 cvt_bf16(float f) {
  union { __bf16 h; u16 u; } c; c.h = (__bf16)f; return c.u;
}
// raw v_exp_f32 (2^x): single transcendental op, no libm range-fixup
__device__ __forceinline__ float fast_exp2(float x) {
  float r;
  asm("v_exp_f32 %0, %1" : "=v"(r) : "v"(x));
  return r;
}
// barrier with LDS-only drain: global loads stay in flight across it
__device__ __forceinline__ void lds_barrier() {
  asm volatile("s_waitcnt lgkmcnt(0)" ::: "memory");
  __builtin_amdgcn_s_barrier();
}

#define MFMA16(a, b, c) __builtin_amdgcn_mfma_f32_16x16x32_bf16((a), (b), (c), 0, 0, 0)

// ---------------------------------------------------------------------------
// proj_qk: Q/K projections with hi/lo bf16 decomposition (~fp32 accuracy).
// Q pre-scaled by log2(e) so attn softmax can use native exp2.
// T14 async-stage split: global loads for iter k+1 are issued BEFORE the
// MFMA phase of iter k and stay in flight across the lds_barriers; the
// cvt+LDS-write happens at the top of iter k+1. Removes the per-iter
// exposed HBM/L2 latency of the old synchronous stage->MFMA loop.
// grid (N/64, 2, B), block 256 (4 waves, each 32x32 via 2x2 16x16 frags)
// ---------------------------------------------------------------------------
__global__ __launch_bounds__(256) void proj_qk(
    const float* __restrict__ x,
    const float* __restrict__ wb, const float* __restrict__ bb,
    const float* __restrict__ wc, const float* __restrict__ bc,
    u16* __restrict__ Qhi, u16* __restrict__ Qlo,
    u16* __restrict__ Khi, u16* __restrict__ Klo)
{
  const int tid = threadIdx.x;
  const int n0 = blockIdx.x * 64;
  const int which = blockIdx.y;
  const int b = blockIdx.z;
  const float* w   = which ? wc : wb;
  const float* bia = which ? bc : bb;
  u16* oh = which ? Khi : Qhi;
  u16* ol = which ? Klo : Qlo;
  const float qsc = which ? 1.0f : 1.44269504088896340736f;  // log2(e) on Q

  __shared__ u16 Wh[64][40], Wl[64][40], Xh[64][40], Xl[64][40];

  const int lane = tid & 63, wid = tid >> 6;
  const int wr = wid >> 1, wn = wid & 1;
  const int l15 = lane & 15, lk = (lane >> 4) * 8;

  // staging coords (fixed per thread)
  const int wrow = tid >> 2, wc0 = (tid & 3) * 8;   // W: 8 floats/thread
  const int xcc = tid >> 3,  xj0 = (tid & 7) * 8;   // X: 8 floats/thread
  const float* wsrc = w + (size_t)wrow * CC + wc0;
  const float* xsrc = x + ((size_t)b * CC + xcc) * NN + n0 + xj0;

  f32x4 acc[2][2] = {};

  // prologue: prefetch kk=0 staging into regs
  f32x4 wv0 = *(const f32x4*)(wsrc), wv1 = *(const f32x4*)(wsrc + 4);
  f32x4 xv0 = *(const f32x4*)(xsrc), xv1 = *(const f32x4*)(xsrc + 4);

  for (int kk = 0; kk < CC; kk += 32) {
    { // write W tile from regs (cvt at write time), packed 16B LDS stores
      u16x8 hh, ll;
#pragma unroll
      for (int r = 0; r < 4; ++r) {
        u16 h = cvt_bf16(wv0[r]);
        hh[r] = h; ll[r] = cvt_bf16(wv0[r] - b2f(h));
      }
#pragma unroll
      for (int r = 0; r < 4; ++r) {
        u16 h = cvt_bf16(wv1[r]);
        hh[4 + r] = h; ll[4 + r] = cvt_bf16(wv1[r] - b2f(h));
      }
      *(u16x8*)&Wh[wrow][wc0] = hh;
      *(u16x8*)&Wl[wrow][wc0] = ll;
    }
    { // write X^T tile from regs (transposed -> scalar LDS stores)
#pragma unroll
      for (int r = 0; r < 4; ++r) {
        u16 h = cvt_bf16(xv0[r]);
        Xh[xj0 + r][xcc] = h;
        Xl[xj0 + r][xcc] = cvt_bf16(xv0[r] - b2f(h));
      }
#pragma unroll
      for (int r = 0; r < 4; ++r) {
        u16 h = cvt_bf16(xv1[r]);
        Xh[xj0 + 4 + r][xcc] = h;
        Xl[xj0 + 4 + r][xcc] = cvt_bf16(xv1[r] - b2f(h));
      }
    }
    lds_barrier();  // LDS writes visible; prefetched globals stay in flight

    // issue next-iter staging loads (hide under MFMA phase)
    if (kk + 32 < CC) {
      wsrc += 32;
      xsrc += (size_t)32 * NN;
      wv0 = *(const f32x4*)(wsrc); wv1 = *(const f32x4*)(wsrc + 4);
      xv0 = *(const f32x4*)(xsrc); xv1 = *(const f32x4*)(xsrc + 4);
    }

#pragma unroll
    for (int fi = 0; fi < 2; ++fi) {
      const int ar = wr * 32 + fi * 16 + l15;
      bf16x8 ah = *(const bf16x8*)&Wh[ar][lk];
      bf16x8 al = *(const bf16x8*)&Wl[ar][lk];
#pragma unroll
      for (int fj = 0; fj < 2; ++fj) {
        const int br = wn * 32 + fj * 16 + l15;
        bf16x8 bh = *(const bf16x8*)&Xh[br][lk];
        bf16x8 bl = *(const bf16x8*)&Xl[br][lk];
        acc[fi][fj] = MFMA16(ah, bh, acc[fi][fj]);
        acc[fi][fj] = MFMA16(ah, bl, acc[fi][fj]);
        acc[fi][fj] = MFMA16(al, bh, acc[fi][fj]);
      }
    }
    lds_barrier();  // all waves' LDS reads done before next write phase
  }

#pragma unroll
  for (int fi = 0; fi < 2; ++fi) {
    const int d0 = wr * 32 + fi * 16 + (lane >> 4) * 4;
#pragma unroll
    for (int fj = 0; fj < 2; ++fj) {
      const int n = n0 + wn * 32 + fj * 16 + l15;
      u16x4 vh, vl;
#pragma unroll
      for (int r = 0; r < 4; ++r) {
        float v = (acc[fi][fj][r] + bia[d0 + r]) * qsc;
        u16 h = cvt_bf16(v);
        vh[r] = h;
        vl[r] = cvt_bf16(v - b2f(h));
      }
      *(u16x4*)&oh[((size_t)b * NN + n) * CK + d0] = vh;
      *(u16x4*)&ol[((size_t)b * NN + n) * CK + d0] = vl;
    }
  }
}

// ---------------------------------------------------------------------------
// proj_v: feat_d projection, plain bf16. Vt[b][o][m] (m-contiguous).
// 128x128 tile (m93 geometry) + T14 async-stage split (prefetch regs for
// iter k+1 before the MFMA phase; lds_barriers keep globals in flight).
// grid (N/128, C/128, B) = (32, 4, 4), block 256, LDS 20KB
// ---------------------------------------------------------------------------
__global__ __launch_bounds__(256) void proj_v(
    const float* __restrict__ x,
    const float* __restrict__ wd, const float* __restrict__ bd,
    u16* __restrict__ Vt)
{
  const int tid = threadIdx.x;
  const int n0 = blockIdx.x * 128;
  const int o0 = blockIdx.y * 128;
  const int b = blockIdx.z;

  __shared__ u16 Wt[128][40], Xt[128][40];
  const int lane = tid & 63, wid = tid >> 6;
  const int wr = wid >> 1, wn = wid & 1;
  const int l15 = lane & 15, lk = (lane >> 4) * 8;

  // staging coords
  const int wrow = tid >> 1, wc0 = (tid & 1) * 16;  // W: 16 floats/thread
  const int xcc = tid >> 3,  xj0 = (tid & 7) * 16;  // X: 16 floats/thread
  const float* wsrc = wd + (size_t)(o0 + wrow) * CC + wc0;
  const float* xsrc = x + ((size_t)b * CC + xcc) * NN + n0 + xj0;

  f32x4 acc[4][4] = {};

  // prologue: prefetch kk=0
  f32x4 wv[4], xv[4];
#pragma unroll
  for (int i = 0; i < 4; ++i) {
    wv[i] = *(const f32x4*)(wsrc + i * 4);
    xv[i] = *(const f32x4*)(xsrc + i * 4);
  }

  for (int kk = 0; kk < CC; kk += 32) {
    { // write W tile from regs
#pragma unroll
      for (int i = 0; i < 4; ++i) {
        u16x4 p;
#pragma unroll
        for (int r = 0; r < 4; ++r) p[r] = cvt_bf16(wv[i][r]);
        *(u16x4*)&Wt[wrow][wc0 + i * 4] = p;
      }
    }
    { // write X^T tile from regs (transposed -> scalar stores)
#pragma unroll
      for (int i = 0; i < 4; ++i)
#pragma unroll
        for (int r = 0; r < 4; ++r)
          Xt[xj0 + i * 4 + r][xcc] = cvt_bf16(xv[i][r]);
    }
    lds_barrier();

    // issue next-iter staging loads (hide under MFMA phase)
    if (kk + 32 < CC) {
      wsrc += 32;
      xsrc += (size_t)32 * NN;
#pragma unroll
      for (int i = 0; i < 4; ++i) {
        wv[i] = *(const f32x4*)(wsrc + i * 4);
        xv[i] = *(const f32x4*)(xsrc + i * 4);
      }
    }

    bf16x8 bvv[4];
#pragma unroll
    for (int fj = 0; fj < 4; ++fj)
      bvv[fj] = *(const bf16x8*)&Xt[wn * 64 + fj * 16 + l15][lk];
#pragma unroll
    for (int fi = 0; fi < 4; ++fi) {
      bf16x8 a = *(const bf16x8*)&Wt[wr * 64 + fi * 16 + l15][lk];
#pragma unroll
      for (int fj = 0; fj < 4; ++fj)
        acc[fi][fj] = MFMA16(a, bvv[fj], acc[fi][fj]);
    }
    lds_barrier();
  }
#pragma unroll
  for (int fi = 0; fi < 4; ++fi) {
    const int d0 = o0 + wr * 64 + fi * 16 + (lane >> 4) * 4;
#pragma unroll
    for (int fj = 0; fj < 4; ++fj) {
      const int n = n0 + wn * 64 + fj * 16 + l15;
#pragma unroll
      for (int r = 0; r < 4; ++r)
        Vt[((size_t)b * CC + d0 + r) * NN + n] = cvt_bf16(acc[fi][fj][r] + bd[d0 + r]);
    }
  }
}

// ---------------------------------------------------------------------------
// attn: flash attention (o-split: 2 blocks per (b,q-tile), each 256 thr =
// 4 waves, 64 q-rows x 256 o-cols; 2 blocks/CU). BYTE-IDENTICAL to r12/r13
// (verified 180.2us, VGPR 96, LDS 43008, 0 conflicts, 21% occupancy).
//   - __launch_bounds__(256, 2) is LOAD-BEARING: hint=2 -> 96 VGPR, 2
//     blocks/CU, 180us. No hint -> 132 VGPR, 1 block/CU, 315us (r11).
//     hint>=3 -> 64-VGPR spill catastrophe (r7/r8). Do not change.
//   - RAW barriers with lgkmcnt-only drain: in-loop cross-wave hazards are
//     all LDS; global loads (V frags, next-K) stay in flight.
//   - log2-domain softmax via raw v_exp_f32 (Q pre-scaled by log2e)
//   - T13 defer-max + gated O-rescale
//   - single K LDS buffer; Q frags in regs; V frags direct from global (L2)
// Structural alternatives all measured WORSE: defer-PV (r6: 181), 32-row
// q-split (r7/r8/r9: 300-394), swapped-QK^T in-reg softmax (r10: 275),
// merged proj_qk (r11: no gain). Do not revisit without new counter evidence.
// grid 512, block 256
// ---------------------------------------------------------------------------
struct alignas(16) AttnLds {
  u16 kh[64][64];
  u16 kl[64][64];
  float s[64][68];   // +4 pad: fp32 score tile
  u16 p[64][64];
  float m[64];
  float l[64];
  float sc[64];
};

__global__ __launch_bounds__(256, 2) void attn(
    const u16* __restrict__ Qhi, const u16* __restrict__ Qlo,
    const u16* __restrict__ Khi, const u16* __restrict__ Klo,
    const u16* __restrict__ Vt,
    const float* __restrict__ x, const float* __restrict__ alpha,
    float* __restrict__ out)
{
  __shared__ AttnLds L;
  const int tid = threadIdx.x;
  const int lane = tid & 63, wid = tid >> 6;   // 4 waves
  const int bid = blockIdx.x;
  // XCD-aware remap: b uses bid bits 1-2 -> batch pinned to one XCD pair
  const int b = (bid >> 1) & 3;
  const int qt = bid >> 3;        // [0,64)
  const int ohalf = bid & 1;      // o-half: columns [ohalf*256, +256)
  const int q0 = qt * 64;
  const int l15 = lane & 15;
  const int lk8 = (lane >> 4) * 8;

  // staging/softmax coords: 4 threads per row, 16 u16 (two u32x4) each
  const int srow = tid >> 2;
  const int sch  = (tid & 3) * 16;
  const int ssw0 = sch ^ ((srow & 7) << 3);
  const int ssw1 = (sch + 8) ^ ((srow & 7) << 3);

  // ---- prologue ----
  // Q fragments (iteration-invariant): wave wid owns score rows wid*16..+15
  bf16x8 qah[2], qal[2];
  {
    const size_t qg = ((size_t)b * NN + q0 + wid * 16 + l15) * CK + lk8;
    qah[0] = *(const bf16x8*)&Qhi[qg];
    qah[1] = *(const bf16x8*)&Qhi[qg + 32];
    qal[0] = *(const bf16x8*)&Qlo[qg];
    qal[1] = *(const bf16x8*)&Qlo[qg + 32];
  }
  { // K tile 0 -> LDS (swizzled)
    const size_t g = ((size_t)b * NN + srow) * CK + sch;
    *(u32x4*)&L.kh[srow][ssw0] = *(const u32x4*)&Khi[g];
    *(u32x4*)&L.kh[srow][ssw1] = *(const u32x4*)&Khi[g + 8];
    *(u32x4*)&L.kl[srow][ssw0] = *(const u32x4*)&Klo[g];
    *(u32x4*)&L.kl[srow][ssw1] = *(const u32x4*)&Klo[g + 8];
  }
  if (tid < 64) { L.m[tid] = -__builtin_huge_valf(); L.l[tid] = 0.f; }

  // per-wave V base: rows o = ohalf*256 + wid*64 + fj*16 + l15
  const u16* vbase = Vt + ((size_t)b * CC + ohalf * 256 + wid * 64 + l15) * NN + lk8;

  f32x4 accO[4][4] = {};  // [q frag][o frag]

  __syncthreads();  // K0 + m/l init visible (full barrier ok in prologue)

  for (int t = 0; t < 64; ++t) {
    const int m0 = t * 64;
    const bool hasNext = (t < 63);

    // --- issue next-K global loads (in flight across barriers) ---
    u32x4 kh0, kh1, kl0, kl1;
    if (hasNext) {
      const size_t g = ((size_t)b * NN + m0 + 64 + srow) * CK + sch;
      kh0 = *(const u32x4*)&Khi[g];
      kh1 = *(const u32x4*)&Khi[g + 8];
      kl0 = *(const u32x4*)&Klo[g];
      kl1 = *(const u32x4*)&Klo[g + 8];
    }
    // --- issue V fragment loads for THIS tile (consumed in PV) ---
    bf16x8 vr[2][4];  // [ks][fj]
#pragma unroll
    for (int f_ = 0; f_ < 4; ++f_)
#pragma unroll
      for (int ks = 0; ks < 2; ++ks)
        vr[ks][f_] = *(const bf16x8*)(vbase + (size_t)f_ * 16 * NN + m0 + ks * 32);

    // --- QK^T: wave wid does score rows wid*16, all 4 col frags ---
    __builtin_amdgcn_s_setprio(1);
#pragma unroll
    for (int fj = 0; fj < 4; ++fj) {
      f32x4 s = {};
#pragma unroll
      for (int ks = 0; ks < 2; ++ks) {
        const int k = ks * 32 + lk8;
        const int br = fj * 16 + l15;
        bf16x8 bh = *(const bf16x8*)&L.kh[br][k ^ ((br & 7) << 3)];
        bf16x8 bl = *(const bf16x8*)&L.kl[br][k ^ ((br & 7) << 3)];
        s = MFMA16(qah[ks], bh, s);
        s = MFMA16(qah[ks], bl, s);
        s = MFMA16(qal[ks], bh, s);
      }
      const int r0 = wid * 16 + (lane >> 4) * 4, c0 = fj * 16 + l15;
#pragma unroll
      for (int r = 0; r < 4; ++r) L.s[r0 + r][c0] = s[r];
    }
    __builtin_amdgcn_s_setprio(0);
    lds_barrier();  // A: s visible; QK^T K-reads + prev p-reads done

    // --- write next K tile (single buffer: reads for t done before A) ---
    if (hasNext) {
      *(u32x4*)&L.kh[srow][ssw0] = kh0;
      *(u32x4*)&L.kh[srow][ssw1] = kh1;
      *(u32x4*)&L.kl[srow][ssw0] = kl0;
      *(u32x4*)&L.kl[srow][ssw1] = kl1;
    }
    // --- online softmax (log2 domain), defer-max: 4 threads/row ---
    {
      const int row = srow, sub = tid & 3;
      const float* sr = &L.s[row][sch];
      f32x4 a0 = *(const f32x4*)&sr[0];
      f32x4 a1 = *(const f32x4*)&sr[4];
      f32x4 a2 = *(const f32x4*)&sr[8];
      f32x4 a3 = *(const f32x4*)&sr[12];
      float mx = fmaxf(fmaxf(fmaxf(a0[0], a0[1]), fmaxf(a0[2], a0[3])),
                       fmaxf(fmaxf(a1[0], a1[1]), fmaxf(a1[2], a1[3])));
      mx = fmaxf(mx, fmaxf(fmaxf(fmaxf(a2[0], a2[1]), fmaxf(a2[2], a2[3])),
                           fmaxf(fmaxf(a3[0], a3[1]), fmaxf(a3[2], a3[3]))));
      mx = fmaxf(mx, __shfl_xor(mx, 1));
      mx = fmaxf(mx, __shfl_xor(mx, 2));
      const float mOld = L.m[row];
      const bool grow = (mx > mOld + 11.5f);  // e^8 in log2 domain (T13)
      const float mNew = grow ? mx : mOld;
      float pv[16];
      float sum = 0.f;
#pragma unroll
      for (int j = 0; j < 4; ++j) { pv[j]      = fast_exp2(a0[j] - mNew); sum += pv[j]; }
#pragma unroll
      for (int j = 0; j < 4; ++j) { pv[4 + j]  = fast_exp2(a1[j] - mNew); sum += pv[4 + j]; }
#pragma unroll
      for (int j = 0; j < 4; ++j) { pv[8 + j]  = fast_exp2(a2[j] - mNew); sum += pv[8 + j]; }
#pragma unroll
      for (int j = 0; j < 4; ++j) { pv[12 + j] = fast_exp2(a3[j] - mNew); sum += pv[12 + j]; }
      sum += __shfl_xor(sum, 1);
      sum += __shfl_xor(sum, 2);
      const float scf = grow ? fast_exp2(mOld - mNew) : 1.0f;
      if (sub == 0) {
        if (grow) L.m[row] = mNew;
        L.l[row] = L.l[row] * scf + sum;
        L.sc[row] = scf;
      }
      u16x8 pb0, pb1;
#pragma unroll
      for (int j = 0; j < 8; ++j) pb0[j] = cvt_bf16(pv[j]);
#pragma unroll
      for (int j = 0; j < 8; ++j) pb1[j] = cvt_bf16(pv[8 + j]);
      *(u16x8*)&L.p[row][ssw0] = pb0;
      *(u16x8*)&L.p[row][ssw1] = pb1;
    }
    lds_barrier();  // B: p + sc + K[t+1] + m/l visible

    // --- gated rescale (usually skipped after warm-up) ---
    {
      f32x4 scv[4];
      bool need = false;
#pragma unroll
      for (int f_ = 0; f_ < 4; ++f_) {
        scv[f_] = *(const f32x4*)&L.sc[f_ * 16 + (lane >> 4) * 4];
        need |= (scv[f_][0] != 1.0f) | (scv[f_][1] != 1.0f) |
                (scv[f_][2] != 1.0f) | (scv[f_][3] != 1.0f);
      }
      if (__any(need)) {
#pragma unroll
        for (int f_ = 0; f_ < 4; ++f_)
#pragma unroll
          for (int fj = 0; fj < 4; ++fj)
#pragma unroll
            for (int r = 0; r < 4; ++r)
              accO[f_][fj][r] *= scv[f_][r];
      }
    }
    // --- PV (V operands already in regs) ---
    __builtin_amdgcn_s_setprio(1);
#pragma unroll
    for (int ks = 0; ks < 2; ++ks) {
      const int k = ks * 32 + lk8;
      bf16x8 a[4];
#pragma unroll
      for (int f_ = 0; f_ < 4; ++f_) {
        const int ar = f_ * 16 + l15;
        a[f_] = *(const bf16x8*)&L.p[ar][k ^ ((ar & 7) << 3)];
      }
#pragma unroll
      for (int fj = 0; fj < 4; ++fj)
#pragma unroll
        for (int f_ = 0; f_ < 4; ++f_)
          accO[f_][fj] = MFMA16(a[f_], vr[ks][fj], accO[f_][fj]);
    }
    __builtin_amdgcn_s_setprio(0);
  }
  __syncthreads();  // full barrier before epilogue (L.l reads)
  // epilogue: out = alpha * (O / l) + x
  const float al = alpha[0];
#pragma unroll
  for (int f_ = 0; f_ < 4; ++f_) {
    const int r0 = f_ * 16 + (lane >> 4) * 4;
    const float rl0 = 1.f / L.l[r0],     rl1 = 1.f / L.l[r0 + 1];
    const float rl2 = 1.f / L.l[r0 + 2], rl3 = 1.f / L.l[r0 + 3];
    const int n_ = q0 + r0;
#pragma unroll
    for (int fj = 0; fj < 4; ++fj) {
      const int c_ = ohalf * 256 + wid * 64 + fj * 16 + l15;
      const size_t g = ((size_t)b * CC + c_) * NN + n_;
      f32x4 xv = *(const f32x4*)&x[g];
      f32x4 ov;
      ov[0] = fmaf(al, accO[f_][fj][0] * rl0, xv[0]);
      ov[1] = fmaf(al, accO[f_][fj][1] * rl1, xv[1]);
      ov[2] = fmaf(al, accO[f_][fj][2] * rl2, xv[2]);
      ov[3] = fmaf(al, accO[f_][fj][3] * rl3, xv[3]);
      *(f32x4*)&out[g] = ov;
    }
  }
}

extern "C" void kernel_launch(void* const* d_in, const int* in_sizes, int n_in,
                              void* d_out, int out_size, void* d_ws, size_t ws_size,
                              hipStream_t stream) {
  const float* x     = (const float*)d_in[0];
  const float* wb    = (const float*)d_in[1];
  const float* bb    = (const float*)d_in[2];
  const float* wc    = (const float*)d_in[3];
  const float* bc    = (const float*)d_in[4];
  const float* wd    = (const float*)d_in[5];
  const float* bd    = (const float*)d_in[6];
  const float* alpha = (const float*)d_in[7];
  float* out = (float*)d_out;

  // workspace: Qhi|Qlo|Khi|Klo (2MB each) + Vt (16MB) = 24MB
  u16* Qhi = (u16*)d_ws;
  u16* Qlo = Qhi + (size_t)NB * NN * CK;
  u16* Khi = Qlo + (size_t)NB * NN * CK;
  u16* Klo = Khi + (size_t)NB * NN * CK;
  u16* Vt  = Klo + (size_t)NB * NN * CK;

  proj_qk<<<dim3(NN / 64, 2, NB), 256, 0, stream>>>(x, wb, bb, wc, bc, Qhi, Qlo, Khi, Klo);
  proj_v<<<dim3(NN / 128, CC / 128, NB), 256, 0, stream>>>(x, wd, bd, Vt);
  attn<<<dim3(512), 256, 0, stream>>>(Qhi, Qlo, Khi, Klo, Vt, x, alpha, out);
}

// Round 15
// 207.106 us; speedup vs baseline: 1.7875x; 1.0227x over previous
//
#include <hip/hip_runtime.h>
#include <hip/hip_bf16.h>

#define NB 4
#define CC 512
#define CK 64
#define NN 4096

typedef unsigned short u16;
typedef __attribute__((ext_vector_type(8))) __bf16 bf16x8;
typedef __attribute__((ext_vector_type(4))) float f32x4;
typedef __attribute__((ext_vector_type(4))) unsigned int u32x4;
typedef __attribute__((ext_vector_type(8))) unsigned short u16x8;
typedef __attribute__((ext_vector_type(4))) unsigned short u16x4;

__device__ __forceinline__ float b2f(u16 u) {
  union { unsigned u; float f; } x; x.u = ((unsigned)u) << 16; return x.f;
}
// native RTNE f32->bf16 cast: 1 VALU op, identical rounding to the manual trick
__device__ __forceinline__ u16 cvt_bf16(float f) {
  union { __bf16 h; u16 u; } c; c.h = (__bf16)f; return c.u;
}
// raw v_exp_f32 (2^x): single transcendental op, no libm range-fixup
__device__ __forceinline__ float fast_exp2(float x) {
  float r;
  asm("v_exp_f32 %0, %1" : "=v"(r) : "v"(x));
  return r;
}
// barrier with LDS-only drain: global loads stay in flight across it
__device__ __forceinline__ void lds_barrier() {
  asm volatile("s_waitcnt lgkmcnt(0)" ::: "memory");
  __builtin_amdgcn_s_barrier();
}

#define MFMA16(a, b, c) __builtin_amdgcn_mfma_f32_16x16x32_bf16((a), (b), (c), 0, 0, 0)

// ---------------------------------------------------------------------------
// proj_fused: proj_qk (blocks 0..511) and proj_v (blocks 512..1023) in ONE
// launch. The two projections are independent (both read only x + weights);
// stream order previously serialized them, idling CUs in each kernel's tail.
// Merged: v-role blocks fill CUs as qk-role blocks retire. Both roles use
// exactly 20480 B LDS (union), 256 threads, block-uniform role branch.
//   qk role: 64-n tile, hi/lo bf16 decomposition, T14 async-stage split,
//            Q pre-scaled by log2(e).
//   v role : 128x128 tile (m93 geometry), plain bf16, T14 async-stage split.
// ---------------------------------------------------------------------------
union ProjLds {
  struct { u16 Wh[64][40], Wl[64][40], Xh[64][40], Xl[64][40]; } qk;  // 20480 B
  struct { u16 Wt[128][40], Xt[128][40]; } v;                         // 20480 B
};

__global__ __launch_bounds__(256) void proj_fused(
    const float* __restrict__ x,
    const float* __restrict__ wb, const float* __restrict__ bb,
    const float* __restrict__ wc, const float* __restrict__ bc,
    const float* __restrict__ wd, const float* __restrict__ bd,
    u16* __restrict__ Qhi, u16* __restrict__ Qlo,
    u16* __restrict__ Khi, u16* __restrict__ Klo,
    u16* __restrict__ Vt)
{
  __shared__ ProjLds P;
  const int tid = threadIdx.x;
  const int lane = tid & 63, wid = tid >> 6;
  const int wr = wid >> 1, wn = wid & 1;
  const int l15 = lane & 15, lk = (lane >> 4) * 8;

  if (blockIdx.x < 512) {
    // ---------------- qk role ----------------
    const int idx = blockIdx.x;
    const int n0 = (idx & 63) * 64;
    const int which = (idx >> 6) & 1;
    const int b = idx >> 7;
    const float* w   = which ? wc : wb;
    const float* bia = which ? bc : bb;
    u16* oh = which ? Khi : Qhi;
    u16* ol = which ? Klo : Qlo;
    const float qsc = which ? 1.0f : 1.44269504088896340736f;  // log2(e) on Q

    auto& Wh = P.qk.Wh; auto& Wl = P.qk.Wl;
    auto& Xh = P.qk.Xh; auto& Xl = P.qk.Xl;

    // staging coords (fixed per thread)
    const int wrow = tid >> 2, wc0 = (tid & 3) * 8;   // W: 8 floats/thread
    const int xcc = tid >> 3,  xj0 = (tid & 7) * 8;   // X: 8 floats/thread
    const float* wsrc = w + (size_t)wrow * CC + wc0;
    const float* xsrc = x + ((size_t)b * CC + xcc) * NN + n0 + xj0;

    f32x4 acc[2][2] = {};

    // prologue: prefetch kk=0 staging into regs
    f32x4 wv0 = *(const f32x4*)(wsrc), wv1 = *(const f32x4*)(wsrc + 4);
    f32x4 xv0 = *(const f32x4*)(xsrc), xv1 = *(const f32x4*)(xsrc + 4);

    for (int kk = 0; kk < CC; kk += 32) {
      { // write W tile from regs, packed 16B LDS stores
        u16x8 hh, ll;
#pragma unroll
        for (int r = 0; r < 4; ++r) {
          u16 h = cvt_bf16(wv0[r]);
          hh[r] = h; ll[r] = cvt_bf16(wv0[r] - b2f(h));
        }
#pragma unroll
        for (int r = 0; r < 4; ++r) {
          u16 h = cvt_bf16(wv1[r]);
          hh[4 + r] = h; ll[4 + r] = cvt_bf16(wv1[r] - b2f(h));
        }
        *(u16x8*)&Wh[wrow][wc0] = hh;
        *(u16x8*)&Wl[wrow][wc0] = ll;
      }
      { // write X^T tile from regs (transposed -> scalar LDS stores)
#pragma unroll
        for (int r = 0; r < 4; ++r) {
          u16 h = cvt_bf16(xv0[r]);
          Xh[xj0 + r][xcc] = h;
          Xl[xj0 + r][xcc] = cvt_bf16(xv0[r] - b2f(h));
        }
#pragma unroll
        for (int r = 0; r < 4; ++r) {
          u16 h = cvt_bf16(xv1[r]);
          Xh[xj0 + 4 + r][xcc] = h;
          Xl[xj0 + 4 + r][xcc] = cvt_bf16(xv1[r] - b2f(h));
        }
      }
      lds_barrier();  // LDS writes visible; prefetched globals in flight

      if (kk + 32 < CC) {  // issue next-iter staging loads
        wsrc += 32;
        xsrc += (size_t)32 * NN;
        wv0 = *(const f32x4*)(wsrc); wv1 = *(const f32x4*)(wsrc + 4);
        xv0 = *(const f32x4*)(xsrc); xv1 = *(const f32x4*)(xsrc + 4);
      }

#pragma unroll
      for (int fi = 0; fi < 2; ++fi) {
        const int ar = wr * 32 + fi * 16 + l15;
        bf16x8 ah = *(const bf16x8*)&Wh[ar][lk];
        bf16x8 al = *(const bf16x8*)&Wl[ar][lk];
#pragma unroll
        for (int fj = 0; fj < 2; ++fj) {
          const int br = wn * 32 + fj * 16 + l15;
          bf16x8 bh = *(const bf16x8*)&Xh[br][lk];
          bf16x8 bl = *(const bf16x8*)&Xl[br][lk];
          acc[fi][fj] = MFMA16(ah, bh, acc[fi][fj]);
          acc[fi][fj] = MFMA16(ah, bl, acc[fi][fj]);
          acc[fi][fj] = MFMA16(al, bh, acc[fi][fj]);
        }
      }
      lds_barrier();  // all waves' LDS reads done before next write phase
    }

#pragma unroll
    for (int fi = 0; fi < 2; ++fi) {
      const int d0 = wr * 32 + fi * 16 + (lane >> 4) * 4;
#pragma unroll
      for (int fj = 0; fj < 2; ++fj) {
        const int n = n0 + wn * 32 + fj * 16 + l15;
        u16x4 vh, vl;
#pragma unroll
        for (int r = 0; r < 4; ++r) {
          float v = (acc[fi][fj][r] + bia[d0 + r]) * qsc;
          u16 h = cvt_bf16(v);
          vh[r] = h;
          vl[r] = cvt_bf16(v - b2f(h));
        }
        *(u16x4*)&oh[((size_t)b * NN + n) * CK + d0] = vh;
        *(u16x4*)&ol[((size_t)b * NN + n) * CK + d0] = vl;
      }
    }
  } else {
    // ---------------- v role ----------------
    const int idx = blockIdx.x - 512;
    const int n0 = (idx & 31) * 128;
    const int o0 = ((idx >> 5) & 3) * 128;
    const int b = idx >> 7;

    auto& Wt = P.v.Wt; auto& Xt = P.v.Xt;

    // staging coords
    const int wrow = tid >> 1, wc0 = (tid & 1) * 16;  // W: 16 floats/thread
    const int xcc = tid >> 3,  xj0 = (tid & 7) * 16;  // X: 16 floats/thread
    const float* wsrc = wd + (size_t)(o0 + wrow) * CC + wc0;
    const float* xsrc = x + ((size_t)b * CC + xcc) * NN + n0 + xj0;

    f32x4 acc[4][4] = {};

    // prologue: prefetch kk=0
    f32x4 wv[4], xv[4];
#pragma unroll
    for (int i = 0; i < 4; ++i) {
      wv[i] = *(const f32x4*)(wsrc + i * 4);
      xv[i] = *(const f32x4*)(xsrc + i * 4);
    }

    for (int kk = 0; kk < CC; kk += 32) {
      { // write W tile from regs
#pragma unroll
        for (int i = 0; i < 4; ++i) {
          u16x4 p;
#pragma unroll
          for (int r = 0; r < 4; ++r) p[r] = cvt_bf16(wv[i][r]);
          *(u16x4*)&Wt[wrow][wc0 + i * 4] = p;
        }
      }
      { // write X^T tile from regs (transposed -> scalar stores)
#pragma unroll
        for (int i = 0; i < 4; ++i)
#pragma unroll
          for (int r = 0; r < 4; ++r)
            Xt[xj0 + i * 4 + r][xcc] = cvt_bf16(xv[i][r]);
      }
      lds_barrier();

      if (kk + 32 < CC) {  // issue next-iter staging loads
        wsrc += 32;
        xsrc += (size_t)32 * NN;
#pragma unroll
        for (int i = 0; i < 4; ++i) {
          wv[i] = *(const f32x4*)(wsrc + i * 4);
          xv[i] = *(const f32x4*)(xsrc + i * 4);
        }
      }

      bf16x8 bvv[4];
#pragma unroll
      for (int fj = 0; fj < 4; ++fj)
        bvv[fj] = *(const bf16x8*)&Xt[wn * 64 + fj * 16 + l15][lk];
#pragma unroll
      for (int fi = 0; fi < 4; ++fi) {
        bf16x8 a = *(const bf16x8*)&Wt[wr * 64 + fi * 16 + l15][lk];
#pragma unroll
        for (int fj = 0; fj < 4; ++fj)
          acc[fi][fj] = MFMA16(a, bvv[fj], acc[fi][fj]);
      }
      lds_barrier();
    }
#pragma unroll
    for (int fi = 0; fi < 4; ++fi) {
      const int d0 = o0 + wr * 64 + fi * 16 + (lane >> 4) * 4;
#pragma unroll
      for (int fj = 0; fj < 4; ++fj) {
        const int n = n0 + wn * 64 + fj * 16 + l15;
#pragma unroll
        for (int r = 0; r < 4; ++r)
          Vt[((size_t)b * CC + d0 + r) * NN + n] = cvt_bf16(acc[fi][fj][r] + bd[d0 + r]);
      }
    }
  }
}

// ---------------------------------------------------------------------------
// attn: flash attention (o-split: 2 blocks per (b,q-tile), each 256 thr =
// 4 waves, 64 q-rows x 256 o-cols; 2 blocks/CU). BYTE-IDENTICAL to r12-r14
// (verified 180.2us, VGPR 96, LDS 43008, 0 conflicts, 21% occupancy).
//   - __launch_bounds__(256, 2) is LOAD-BEARING: hint=2 -> 96 VGPR, 2
//     blocks/CU, 180us. No hint -> 132 VGPR, 1 block/CU, 315us (r11).
//     hint>=3 -> 64-VGPR spill catastrophe (r7/r8). Do not change.
//   - RAW barriers with lgkmcnt-only drain: in-loop cross-wave hazards are
//     all LDS; global loads (V frags, next-K) stay in flight.
//   - log2-domain softmax via raw v_exp_f32 (Q pre-scaled by log2e)
//   - T13 defer-max + gated O-rescale
//   - single K LDS buffer; Q frags in regs; V frags direct from global (L2)
// Structural alternatives all measured WORSE: defer-PV (r6: 181), 32-row
// q-split (r7/r8/r9: 300-394), swapped-QK^T in-reg softmax (r10: 275),
// merged proj_qk (r11: no gain). Do not revisit without new counter evidence.
// grid 512, block 256
// ---------------------------------------------------------------------------
struct alignas(16) AttnLds {
  u16 kh[64][64];
  u16 kl[64][64];
  float s[64][68];   // +4 pad: fp32 score tile
  u16 p[64][64];
  float m[64];
  float l[64];
  float sc[64];
};

__global__ __launch_bounds__(256, 2) void attn(
    const u16* __restrict__ Qhi, const u16* __restrict__ Qlo,
    const u16* __restrict__ Khi, const u16* __restrict__ Klo,
    const u16* __restrict__ Vt,
    const float* __restrict__ x, const float* __restrict__ alpha,
    float* __restrict__ out)
{
  __shared__ AttnLds L;
  const int tid = threadIdx.x;
  const int lane = tid & 63, wid = tid >> 6;   // 4 waves
  const int bid = blockIdx.x;
  // XCD-aware remap: b uses bid bits 1-2 -> batch pinned to one XCD pair
  const int b = (bid >> 1) & 3;
  const int qt = bid >> 3;        // [0,64)
  const int ohalf = bid & 1;      // o-half: columns [ohalf*256, +256)
  const int q0 = qt * 64;
  const int l15 = lane & 15;
  const int lk8 = (lane >> 4) * 8;

  // staging/softmax coords: 4 threads per row, 16 u16 (two u32x4) each
  const int srow = tid >> 2;
  const int sch  = (tid & 3) * 16;
  const int ssw0 = sch ^ ((srow & 7) << 3);
  const int ssw1 = (sch + 8) ^ ((srow & 7) << 3);

  // ---- prologue ----
  // Q fragments (iteration-invariant): wave wid owns score rows wid*16..+15
  bf16x8 qah[2], qal[2];
  {
    const size_t qg = ((size_t)b * NN + q0 + wid * 16 + l15) * CK + lk8;
    qah[0] = *(const bf16x8*)&Qhi[qg];
    qah[1] = *(const bf16x8*)&Qhi[qg + 32];
    qal[0] = *(const bf16x8*)&Qlo[qg];
    qal[1] = *(const bf16x8*)&Qlo[qg + 32];
  }
  { // K tile 0 -> LDS (swizzled)
    const size_t g = ((size_t)b * NN + srow) * CK + sch;
    *(u32x4*)&L.kh[srow][ssw0] = *(const u32x4*)&Khi[g];
    *(u32x4*)&L.kh[srow][ssw1] = *(const u32x4*)&Khi[g + 8];
    *(u32x4*)&L.kl[srow][ssw0] = *(const u32x4*)&Klo[g];
    *(u32x4*)&L.kl[srow][ssw1] = *(const u32x4*)&Klo[g + 8];
  }
  if (tid < 64) { L.m[tid] = -__builtin_huge_valf(); L.l[tid] = 0.f; }

  // per-wave V base: rows o = ohalf*256 + wid*64 + fj*16 + l15
  const u16* vbase = Vt + ((size_t)b * CC + ohalf * 256 + wid * 64 + l15) * NN + lk8;

  f32x4 accO[4][4] = {};  // [q frag][o frag]

  __syncthreads();  // K0 + m/l init visible (full barrier ok in prologue)

  for (int t = 0; t < 64; ++t) {
    const int m0 = t * 64;
    const bool hasNext = (t < 63);

    // --- issue next-K global loads (in flight across barriers) ---
    u32x4 kh0, kh1, kl0, kl1;
    if (hasNext) {
      const size_t g = ((size_t)b * NN + m0 + 64 + srow) * CK + sch;
      kh0 = *(const u32x4*)&Khi[g];
      kh1 = *(const u32x4*)&Khi[g + 8];
      kl0 = *(const u32x4*)&Klo[g];
      kl1 = *(const u32x4*)&Klo[g + 8];
    }
    // --- issue V fragment loads for THIS tile (consumed in PV) ---
    bf16x8 vr[2][4];  // [ks][fj]
#pragma unroll
    for (int f_ = 0; f_ < 4; ++f_)
#pragma unroll
      for (int ks = 0; ks < 2; ++ks)
        vr[ks][f_] = *(const bf16x8*)(vbase + (size_t)f_ * 16 * NN + m0 + ks * 32);

    // --- QK^T: wave wid does score rows wid*16, all 4 col frags ---
    __builtin_amdgcn_s_setprio(1);
#pragma unroll
    for (int fj = 0; fj < 4; ++fj) {
      f32x4 s = {};
#pragma unroll
      for (int ks = 0; ks < 2; ++ks) {
        const int k = ks * 32 + lk8;
        const int br = fj * 16 + l15;
        bf16x8 bh = *(const bf16x8*)&L.kh[br][k ^ ((br & 7) << 3)];
        bf16x8 bl = *(const bf16x8*)&L.kl[br][k ^ ((br & 7) << 3)];
        s = MFMA16(qah[ks], bh, s);
        s = MFMA16(qah[ks], bl, s);
        s = MFMA16(qal[ks], bh, s);
      }
      const int r0 = wid * 16 + (lane >> 4) * 4, c0 = fj * 16 + l15;
#pragma unroll
      for (int r = 0; r < 4; ++r) L.s[r0 + r][c0] = s[r];
    }
    __builtin_amdgcn_s_setprio(0);
    lds_barrier();  // A: s visible; QK^T K-reads + prev p-reads done

    // --- write next K tile (single buffer: reads for t done before A) ---
    if (hasNext) {
      *(u32x4*)&L.kh[srow][ssw0] = kh0;
      *(u32x4*)&L.kh[srow][ssw1] = kh1;
      *(u32x4*)&L.kl[srow][ssw0] = kl0;
      *(u32x4*)&L.kl[srow][ssw1] = kl1;
    }
    // --- online softmax (log2 domain), defer-max: 4 threads/row ---
    {
      const int row = srow, sub = tid & 3;
      const float* sr = &L.s[row][sch];
      f32x4 a0 = *(const f32x4*)&sr[0];
      f32x4 a1 = *(const f32x4*)&sr[4];
      f32x4 a2 = *(const f32x4*)&sr[8];
      f32x4 a3 = *(const f32x4*)&sr[12];
      float mx = fmaxf(fmaxf(fmaxf(a0[0], a0[1]), fmaxf(a0[2], a0[3])),
                       fmaxf(fmaxf(a1[0], a1[1]), fmaxf(a1[2], a1[3])));
      mx = fmaxf(mx, fmaxf(fmaxf(fmaxf(a2[0], a2[1]), fmaxf(a2[2], a2[3])),
                           fmaxf(fmaxf(a3[0], a3[1]), fmaxf(a3[2], a3[3]))));
      mx = fmaxf(mx, __shfl_xor(mx, 1));
      mx = fmaxf(mx, __shfl_xor(mx, 2));
      const float mOld = L.m[row];
      const bool grow = (mx > mOld + 11.5f);  // e^8 in log2 domain (T13)
      const float mNew = grow ? mx : mOld;
      float pv[16];
      float sum = 0.f;
#pragma unroll
      for (int j = 0; j < 4; ++j) { pv[j]      = fast_exp2(a0[j] - mNew); sum += pv[j]; }
#pragma unroll
      for (int j = 0; j < 4; ++j) { pv[4 + j]  = fast_exp2(a1[j] - mNew); sum += pv[4 + j]; }
#pragma unroll
      for (int j = 0; j < 4; ++j) { pv[8 + j]  = fast_exp2(a2[j] - mNew); sum += pv[8 + j]; }
#pragma unroll
      for (int j = 0; j < 4; ++j) { pv[12 + j] = fast_exp2(a3[j] - mNew); sum += pv[12 + j]; }
      sum += __shfl_xor(sum, 1);
      sum += __shfl_xor(sum, 2);
      const float scf = grow ? fast_exp2(mOld - mNew) : 1.0f;
      if (sub == 0) {
        if (grow) L.m[row] = mNew;
        L.l[row] = L.l[row] * scf + sum;
        L.sc[row] = scf;
      }
      u16x8 pb0, pb1;
#pragma unroll
      for (int j = 0; j < 8; ++j) pb0[j] = cvt_bf16(pv[j]);
#pragma unroll
      for (int j = 0; j < 8; ++j) pb1[j] = cvt_bf16(pv[8 + j]);
      *(u16x8*)&L.p[row][ssw0] = pb0;
      *(u16x8*)&L.p[row][ssw1] = pb1;
    }
    lds_barrier();  // B: p + sc + K[t+1] + m/l visible

    // --- gated rescale (usually skipped after warm-up) ---
    {
      f32x4 scv[4];
      bool need = false;
#pragma unroll
      for (int f_ = 0; f_ < 4; ++f_) {
        scv[f_] = *(const f32x4*)&L.sc[f_ * 16 + (lane >> 4) * 4];
        need |= (scv[f_][0] != 1.0f) | (scv[f_][1] != 1.0f) |
                (scv[f_][2] != 1.0f) | (scv[f_][3] != 1.0f);
      }
      if (__any(need)) {
#pragma unroll
        for (int f_ = 0; f_ < 4; ++f_)
#pragma unroll
          for (int fj = 0; fj < 4; ++fj)
#pragma unroll
            for (int r = 0; r < 4; ++r)
              accO[f_][fj][r] *= scv[f_][r];
      }
    }
    // --- PV (V operands already in regs) ---
    __builtin_amdgcn_s_setprio(1);
#pragma unroll
    for (int ks = 0; ks < 2; ++ks) {
      const int k = ks * 32 + lk8;
      bf16x8 a[4];
#pragma unroll
      for (int f_ = 0; f_ < 4; ++f_) {
        const int ar = f_ * 16 + l15;
        a[f_] = *(const bf16x8*)&L.p[ar][k ^ ((ar & 7) << 3)];
      }
#pragma unroll
      for (int fj = 0; fj < 4; ++fj)
#pragma unroll
        for (int f_ = 0; f_ < 4; ++f_)
          accO[f_][fj] = MFMA16(a[f_], vr[ks][fj], accO[f_][fj]);
    }
    __builtin_amdgcn_s_setprio(0);
  }
  __syncthreads();  // full barrier before epilogue (L.l reads)
  // epilogue: out = alpha * (O / l) + x
  const float al = alpha[0];
#pragma unroll
  for (int f_ = 0; f_ < 4; ++f_) {
    const int r0 = f_ * 16 + (lane >> 4) * 4;
    const float rl0 = 1.f / L.l[r0],     rl1 = 1.f / L.l[r0 + 1];
    const float rl2 = 1.f / L.l[r0 + 2], rl3 = 1.f / L.l[r0 + 3];
    const int n_ = q0 + r0;
#pragma unroll
    for (int fj = 0; fj < 4; ++fj) {
      const int c_ = ohalf * 256 + wid * 64 + fj * 16 + l15;
      const size_t g = ((size_t)b * CC + c_) * NN + n_;
      f32x4 xv = *(const f32x4*)&x[g];
      f32x4 ov;
      ov[0] = fmaf(al, accO[f_][fj][0] * rl0, xv[0]);
      ov[1] = fmaf(al, accO[f_][fj][1] * rl1, xv[1]);
      ov[2] = fmaf(al, accO[f_][fj][2] * rl2, xv[2]);
      ov[3] = fmaf(al, accO[f_][fj][3] * rl3, xv[3]);
      *(f32x4*)&out[g] = ov;
    }
  }
}

extern "C" void kernel_launch(void* const* d_in, const int* in_sizes, int n_in,
                              void* d_out, int out_size, void* d_ws, size_t ws_size,
                              hipStream_t stream) {
  const float* x     = (const float*)d_in[0];
  const float* wb    = (const float*)d_in[1];
  const float* bb    = (const float*)d_in[2];
  const float* wc    = (const float*)d_in[3];
  const float* bc    = (const float*)d_in[4];
  const float* wd    = (const float*)d_in[5];
  const float* bd    = (const float*)d_in[6];
  const float* alpha = (const float*)d_in[7];
  float* out = (float*)d_out;

  // workspace: Qhi|Qlo|Khi|Klo (2MB each) + Vt (16MB) = 24MB
  u16* Qhi = (u16*)d_ws;
  u16* Qlo = Qhi + (size_t)NB * NN * CK;
  u16* Khi = Qlo + (size_t)NB * NN * CK;
  u16* Klo = Khi + (size_t)NB * NN * CK;
  u16* Vt  = Klo + (size_t)NB * NN * CK;

  proj_fused<<<dim3(1024), 256, 0, stream>>>(x, wb, bb, wc, bc, wd, bd,
                                             Qhi, Qlo, Khi, Klo, Vt);
  attn<<<dim3(512), 256, 0, stream>>>(Qhi, Qlo, Khi, Klo, Vt, x, alpha, out);
}